// Round 1
// baseline (308.691 us; speedup 1.0000x reference)
//
#include <hip/hip_runtime.h>
#include <math.h>

#define NQ 7
#define DIM 128
#define NLAYERS 3

// ---------------------------------------------------------------------------
// Precompute: trig table for weight angles (batch-uniform) + transpose fus_w1
// trig[(l*NQ+i)*4 + {0,1,2,3}] = cos(wry/2), sin(wry/2), cos(wrz/2), sin(wrz/2)
// w1t[j*110 + k] = fus_w1[k*128 + j]
// ---------------------------------------------------------------------------
__global__ __launch_bounds__(256) void precompute_kernel(
    const float* __restrict__ wry, const float* __restrict__ wrz,
    const float* __restrict__ fus_w1,
    float* __restrict__ w1t, float* __restrict__ trig)
{
    int tid = threadIdx.x;
    if (tid < NLAYERS * NQ) {
        float hy = 0.5f * wry[tid];
        float hz = 0.5f * wrz[tid];
        trig[tid * 4 + 0] = cosf(hy);
        trig[tid * 4 + 1] = sinf(hy);
        trig[tid * 4 + 2] = cosf(hz);
        trig[tid * 4 + 3] = sinf(hz);
    }
    for (int idx = tid; idx < 110 * 128; idx += 256) {
        int k = idx >> 7;        // 0..109
        int j = idx & 127;       // 0..127
        w1t[j * 110 + k] = fus_w1[idx];
    }
}

// ---------------------------------------------------------------------------
// Quantum circuit: one wave (64 lanes) per batch element.
// Lane holds amplitudes for indices lane (a0) and lane+64 (a1).
// Qubit q acts on bit p = 6-q of the state index.
// ---------------------------------------------------------------------------
__global__ __launch_bounds__(256) void circuit_kernel(
    const float* __restrict__ x_q, const float* __restrict__ scales,
    const float* __restrict__ biases, const float* __restrict__ trig,
    float* __restrict__ q_out, int B)
{
    int gtid = blockIdx.x * blockDim.x + threadIdx.x;
    int wave = gtid >> 6;
    int lane = threadIdx.x & 63;
    if (wave >= B) return;

    // Data-angle trig (reused across all 3 layers)
    float dc[NQ], dsn[NQ];
#pragma unroll
    for (int i = 0; i < NQ; ++i) {
        float ang = scales[i] * x_q[wave * NQ + i] + biases[i];
        float h = 0.5f * ang;
        dc[i]  = cosf(h);
        dsn[i] = sinf(h);
    }

    float a0r = (lane == 0) ? 1.0f : 0.0f, a0i = 0.0f;
    float a1r = 0.0f, a1i = 0.0f;

    auto RY = [&](float c, float s, int q) {
        int p = 6 - q;
        if (p == 6) {
            // pair (a0, a1) within lane
            float n0r = c * a0r - s * a1r;
            float n0i = c * a0i - s * a1i;
            float n1r = s * a0r + c * a1r;
            float n1i = s * a0i + c * a1i;
            a0r = n0r; a0i = n0i; a1r = n1r; a1i = n1i;
        } else {
            int m = 1 << p;
            float sg = (lane & m) ? s : -s;
            float p0r = __shfl_xor(a0r, m, 64);
            float p0i = __shfl_xor(a0i, m, 64);
            float p1r = __shfl_xor(a1r, m, 64);
            float p1i = __shfl_xor(a1i, m, 64);
            a0r = fmaf(c, a0r, sg * p0r);
            a0i = fmaf(c, a0i, sg * p0i);
            a1r = fmaf(c, a1r, sg * p1r);
            a1i = fmaf(c, a1i, sg * p1i);
        }
    };

    auto RZ = [&](float c, float s, int q) {
        int p = 6 - q;
        if (p == 6) {
            // a0 has bit=0: mult by (c,-s); a1 has bit=1: mult by (c,+s)
            float n0r = c * a0r + s * a0i;
            float n0i = c * a0i - s * a0r;
            float n1r = c * a1r - s * a1i;
            float n1i = c * a1i + s * a1r;
            a0r = n0r; a0i = n0i; a1r = n1r; a1i = n1i;
        } else {
            float se = (lane & (1 << p)) ? s : -s;
            float n0r = c * a0r - se * a0i;
            float n0i = c * a0i + se * a0r;
            float n1r = c * a1r - se * a1i;
            float n1i = c * a1i + se * a1r;
            a0r = n0r; a0i = n0i; a1r = n1r; a1i = n1i;
        }
    };

    auto CNOT = [&](int cq, int tq) {
        int pc = 6 - cq, pt = 6 - tq;
        if (pc == 6) {
            // control = bit6: a0 unchanged; a1 gathers with bit pt flipped
            int m = 1 << pt;
            a1r = __shfl_xor(a1r, m, 64);
            a1i = __shfl_xor(a1i, m, 64);
        } else if (pt == 6) {
            // target = bit6: lanes with control bit set swap a0<->a1
            bool sw = (lane & (1 << pc)) != 0;
            float t0r = sw ? a1r : a0r, t0i = sw ? a1i : a0i;
            float t1r = sw ? a0r : a1r, t1i = sw ? a0i : a1i;
            a0r = t0r; a0i = t0i; a1r = t1r; a1i = t1i;
        } else {
            int src = lane ^ (((lane >> pc) & 1) << pt);
            a0r = __shfl(a0r, src, 64);
            a0i = __shfl(a0i, src, 64);
            a1r = __shfl(a1r, src, 64);
            a1i = __shfl(a1i, src, 64);
        }
    };

#pragma unroll
    for (int layer = 0; layer < NLAYERS; ++layer) {
#pragma unroll
        for (int i = 0; i < NQ; ++i) RY(dc[i], dsn[i], i);
#pragma unroll
        for (int i = 0; i < NQ; ++i) {
            int t4 = (layer * NQ + i) * 4;
            float cy = trig[t4 + 0], sy = trig[t4 + 1];
            float cz = trig[t4 + 2], sz = trig[t4 + 3];
            RY(cy, sy, i);
            RZ(cz, sz, i);
        }
        int shift = layer + 1;
#pragma unroll
        for (int i = 0; i < NQ; ++i) CNOT(i, (i + shift) % NQ);
    }

    // probabilities
    float p0 = a0r * a0r + a0i * a0i;
    float p1 = a1r * a1r + a1i * a1i;
    float tp = p0 + p1;   // for sign masks not involving bit6
    float tm = p0 - p1;   // for sign masks involving bit6

    // Walsh-Hadamard over the 6 lane bits: lane L ends with
    // W[L] = sum_m v[m] * (-1)^popcount(L & m)
#pragma unroll
    for (int s = 0; s < 6; ++s) {
        int m = 1 << s;
        float pp = __shfl_xor(tp, m, 64);
        float pm = __shfl_xor(tm, m, 64);
        tp = (lane & m) ? (pp - tp) : (tp + pp);
        tm = (lane & m) ? (pm - tm) : (tm + pm);
    }

    // Feature extraction:
    //  SZ_0  = Wm[0]          SZZ_0 = Wm[32]        SZZ_6 = Wm[1]
    //  SZ_i  = Wp[1<<(6-i)]   (i=1..6)
    //  SZZ_i = Wp[(1<<(6-i)) | (1<<(5-i))]  (i=1..5)
    float* qo = q_out + (size_t)wave * 14;
    int fp = -1;
    switch (lane) {
        case 32: fp = 1;  break;
        case 16: fp = 2;  break;
        case 8:  fp = 3;  break;
        case 4:  fp = 4;  break;
        case 2:  fp = 5;  break;
        case 1:  fp = 6;  break;
        case 48: fp = 8;  break;
        case 24: fp = 9;  break;
        case 12: fp = 10; break;
        case 6:  fp = 11; break;
        case 3:  fp = 12; break;
        default: break;
    }
    if (fp >= 0)    qo[fp] = tp;
    if (lane == 0)  qo[0]  = tm;
    if (lane == 32) qo[7]  = tm;
    if (lane == 1)  qo[13] = tm;
}

// ---------------------------------------------------------------------------
// Encoder: thread-per-row.  c_enc = relu(relu(x_c@W1+b1)@W2+b2)
// ---------------------------------------------------------------------------
__global__ __launch_bounds__(256) void encoder_kernel(
    const float* __restrict__ x_c,
    const float* __restrict__ w1, const float* __restrict__ b1,
    const float* __restrict__ w2, const float* __restrict__ b2,
    float* __restrict__ c_enc, int B)
{
    int r = blockIdx.x * blockDim.x + threadIdx.x;
    if (r >= B) return;

    float x[64];
    const float4* xr = (const float4*)(x_c + (size_t)r * 64);
#pragma unroll
    for (int k = 0; k < 16; ++k) {
        float4 v = xr[k];
        x[4 * k + 0] = v.x; x[4 * k + 1] = v.y;
        x[4 * k + 2] = v.z; x[4 * k + 3] = v.w;
    }

    float h[64];
#pragma unroll
    for (int j = 0; j < 64; ++j) h[j] = b1[j];
#pragma unroll 4
    for (int k = 0; k < 64; ++k) {
        float xk = x[k];
#pragma unroll
        for (int j = 0; j < 64; ++j) h[j] = fmaf(xk, w1[k * 64 + j], h[j]);
    }

    float e[32];
#pragma unroll
    for (int j = 0; j < 32; ++j) e[j] = b2[j];
#pragma unroll 4
    for (int k = 0; k < 64; ++k) {
        float hk = fmaxf(h[k], 0.0f);
#pragma unroll
        for (int j = 0; j < 32; ++j) e[j] = fmaf(hk, w2[k * 32 + j], e[j]);
    }

    float* out = c_enc + (size_t)r * 32;
#pragma unroll
    for (int j = 0; j < 32; ++j) out[j] = fmaxf(e[j], 0.0f);
}

// ---------------------------------------------------------------------------
// Fusion MLP: thread-per-row. comb(110) -> 128 -> 64 -> 32 -> 1
// w1t is transposed fus_w1: w1t[j*110+k].
// h1 is consumed on the fly into h2 accumulators (saves registers).
// ---------------------------------------------------------------------------
__global__ __launch_bounds__(256) void fusion_kernel(
    const float* __restrict__ q_out, const float* __restrict__ c_enc,
    const float* __restrict__ x_c,
    const float* __restrict__ w1t, const float* __restrict__ b1,
    const float* __restrict__ w2,  const float* __restrict__ b2,
    const float* __restrict__ w3,  const float* __restrict__ b3,
    const float* __restrict__ w4,  const float* __restrict__ b4,
    float* __restrict__ out, int B)
{
    int r = blockIdx.x * blockDim.x + threadIdx.x;
    if (r >= B) return;

    float comb[110];
#pragma unroll
    for (int k = 0; k < 14; ++k) comb[k] = q_out[(size_t)r * 14 + k];
#pragma unroll
    for (int k = 0; k < 32; ++k) comb[14 + k] = c_enc[(size_t)r * 32 + k];
    const float4* xr = (const float4*)(x_c + (size_t)r * 64);
#pragma unroll
    for (int k = 0; k < 16; ++k) {
        float4 v = xr[k];
        comb[46 + 4 * k + 0] = v.x; comb[46 + 4 * k + 1] = v.y;
        comb[46 + 4 * k + 2] = v.z; comb[46 + 4 * k + 3] = v.w;
    }

    float h2[64];
#pragma unroll
    for (int j = 0; j < 64; ++j) h2[j] = b2[j];

#pragma unroll 1
    for (int j = 0; j < 128; ++j) {
        const float* w = w1t + j * 110;
        float acc0 = 0.f, acc1 = 0.f, acc2 = 0.f, acc3 = 0.f;
#pragma unroll
        for (int k = 0; k < 108; k += 4) {
            acc0 = fmaf(comb[k + 0], w[k + 0], acc0);
            acc1 = fmaf(comb[k + 1], w[k + 1], acc1);
            acc2 = fmaf(comb[k + 2], w[k + 2], acc2);
            acc3 = fmaf(comb[k + 3], w[k + 3], acc3);
        }
        acc0 = fmaf(comb[108], w[108], acc0);
        acc1 = fmaf(comb[109], w[109], acc1);
        float t = fmaxf((acc0 + acc1) + (acc2 + acc3) + b1[j], 0.0f);
#pragma unroll
        for (int j2 = 0; j2 < 64; ++j2)
            h2[j2] = fmaf(t, w2[j * 64 + j2], h2[j2]);
    }

    float h3[32];
#pragma unroll
    for (int j = 0; j < 32; ++j) h3[j] = b3[j];
#pragma unroll 2
    for (int j = 0; j < 64; ++j) {
        float t = fmaxf(h2[j], 0.0f);
#pragma unroll
        for (int j2 = 0; j2 < 32; ++j2)
            h3[j2] = fmaf(t, w3[j * 32 + j2], h3[j2]);
    }

    float acc = b4[0];
#pragma unroll
    for (int j = 0; j < 32; ++j)
        acc = fmaf(fmaxf(h3[j], 0.0f), w4[j], acc);

    out[r] = acc;
}

// ---------------------------------------------------------------------------
extern "C" void kernel_launch(void* const* d_in, const int* in_sizes, int n_in,
                              void* d_out, int out_size, void* d_ws, size_t ws_size,
                              hipStream_t stream)
{
    const float* x_q     = (const float*)d_in[0];
    const float* x_c     = (const float*)d_in[1];
    const float* scales  = (const float*)d_in[2];
    const float* biases  = (const float*)d_in[3];
    const float* wry     = (const float*)d_in[4];
    const float* wrz     = (const float*)d_in[5];
    const float* enc_w1  = (const float*)d_in[6];
    const float* enc_b1  = (const float*)d_in[7];
    const float* enc_w2  = (const float*)d_in[8];
    const float* enc_b2  = (const float*)d_in[9];
    const float* fus_w1  = (const float*)d_in[10];
    const float* fus_b1  = (const float*)d_in[11];
    const float* fus_w2  = (const float*)d_in[12];
    const float* fus_b2  = (const float*)d_in[13];
    const float* fus_w3  = (const float*)d_in[14];
    const float* fus_b3  = (const float*)d_in[15];
    const float* fus_w4  = (const float*)d_in[16];
    const float* fus_b4  = (const float*)d_in[17];
    float* out = (float*)d_out;

    int B = in_sizes[0] / NQ;   // 32768

    // workspace layout (floats)
    float* ws    = (float*)d_ws;
    float* q_out = ws;                          // B*14
    float* c_enc = ws + (size_t)B * 14;         // B*32
    float* w1t   = c_enc + (size_t)B * 32;      // 128*110
    float* trig  = w1t + 128 * 110;             // 3*7*4

    precompute_kernel<<<1, 256, 0, stream>>>(wry, wrz, fus_w1, w1t, trig);

    int circ_blocks = (B * 64 + 255) / 256;
    circuit_kernel<<<circ_blocks, 256, 0, stream>>>(x_q, scales, biases, trig,
                                                    q_out, B);

    int row_blocks = (B + 255) / 256;
    encoder_kernel<<<row_blocks, 256, 0, stream>>>(x_c, enc_w1, enc_b1,
                                                   enc_w2, enc_b2, c_enc, B);

    fusion_kernel<<<row_blocks, 256, 0, stream>>>(q_out, c_enc, x_c,
                                                  w1t, fus_b1, fus_w2, fus_b2,
                                                  fus_w3, fus_b3, fus_w4, fus_b4,
                                                  out, B);
}

// Round 2
// 123.720 us; speedup vs baseline: 2.4951x; 2.4951x over previous
//
#include <hip/hip_runtime.h>
#include <math.h>

#define NQ 7
#define DIM 128
#define NLAYERS 3
#define ROWS 64
#define S1 65   // padded row stride of A1 (pad only matters for staging writes)

// ---------------------------------------------------------------------------
// Precompute: trig table for weight angles (batch-uniform)
// trig[(l*NQ+i)*4 + {0,1,2,3}] = cos(wry/2), sin(wry/2), cos(wrz/2), sin(wrz/2)
// ---------------------------------------------------------------------------
__global__ __launch_bounds__(64) void precompute_kernel(
    const float* __restrict__ wry, const float* __restrict__ wrz,
    float* __restrict__ trig)
{
    int tid = threadIdx.x;
    if (tid < NLAYERS * NQ) {
        float hy = 0.5f * wry[tid];
        float hz = 0.5f * wrz[tid];
        trig[tid * 4 + 0] = cosf(hy);
        trig[tid * 4 + 1] = sinf(hy);
        trig[tid * 4 + 2] = cosf(hz);
        trig[tid * 4 + 3] = sinf(hz);
    }
}

// ---------------------------------------------------------------------------
// Quantum circuit: one wave (64 lanes) per batch element.
// Lane holds amplitudes for indices lane (a0) and lane+64 (a1).
// Qubit q acts on bit p = 6-q of the state index.
// ---------------------------------------------------------------------------
__global__ __launch_bounds__(256) void circuit_kernel(
    const float* __restrict__ x_q, const float* __restrict__ scales,
    const float* __restrict__ biases, const float* __restrict__ trig,
    float* __restrict__ q_out, int B)
{
    int gtid = blockIdx.x * blockDim.x + threadIdx.x;
    int wave = gtid >> 6;
    int lane = threadIdx.x & 63;
    if (wave >= B) return;

    // Data-angle trig (reused across all 3 layers)
    float dc[NQ], dsn[NQ];
#pragma unroll
    for (int i = 0; i < NQ; ++i) {
        float ang = scales[i] * x_q[wave * NQ + i] + biases[i];
        float h = 0.5f * ang;
        dc[i]  = cosf(h);
        dsn[i] = sinf(h);
    }

    float a0r = (lane == 0) ? 1.0f : 0.0f, a0i = 0.0f;
    float a1r = 0.0f, a1i = 0.0f;

    auto RY = [&](float c, float s, int q) {
        int p = 6 - q;
        if (p == 6) {
            float n0r = c * a0r - s * a1r;
            float n0i = c * a0i - s * a1i;
            float n1r = s * a0r + c * a1r;
            float n1i = s * a0i + c * a1i;
            a0r = n0r; a0i = n0i; a1r = n1r; a1i = n1i;
        } else {
            int m = 1 << p;
            float sg = (lane & m) ? s : -s;
            float p0r = __shfl_xor(a0r, m, 64);
            float p0i = __shfl_xor(a0i, m, 64);
            float p1r = __shfl_xor(a1r, m, 64);
            float p1i = __shfl_xor(a1i, m, 64);
            a0r = fmaf(c, a0r, sg * p0r);
            a0i = fmaf(c, a0i, sg * p0i);
            a1r = fmaf(c, a1r, sg * p1r);
            a1i = fmaf(c, a1i, sg * p1i);
        }
    };

    auto RZ = [&](float c, float s, int q) {
        int p = 6 - q;
        if (p == 6) {
            float n0r = c * a0r + s * a0i;
            float n0i = c * a0i - s * a0r;
            float n1r = c * a1r - s * a1i;
            float n1i = c * a1i + s * a1r;
            a0r = n0r; a0i = n0i; a1r = n1r; a1i = n1i;
        } else {
            float se = (lane & (1 << p)) ? s : -s;
            float n0r = c * a0r - se * a0i;
            float n0i = c * a0i + se * a0r;
            float n1r = c * a1r - se * a1i;
            float n1i = c * a1i + se * a1r;
            a0r = n0r; a0i = n0i; a1r = n1r; a1i = n1i;
        }
    };

    auto CNOT = [&](int cq, int tq) {
        int pc = 6 - cq, pt = 6 - tq;
        if (pc == 6) {
            int m = 1 << pt;
            a1r = __shfl_xor(a1r, m, 64);
            a1i = __shfl_xor(a1i, m, 64);
        } else if (pt == 6) {
            bool sw = (lane & (1 << pc)) != 0;
            float t0r = sw ? a1r : a0r, t0i = sw ? a1i : a0i;
            float t1r = sw ? a0r : a1r, t1i = sw ? a0i : a1i;
            a0r = t0r; a0i = t0i; a1r = t1r; a1i = t1i;
        } else {
            int src = lane ^ (((lane >> pc) & 1) << pt);
            a0r = __shfl(a0r, src, 64);
            a0i = __shfl(a0i, src, 64);
            a1r = __shfl(a1r, src, 64);
            a1i = __shfl(a1i, src, 64);
        }
    };

#pragma unroll
    for (int layer = 0; layer < NLAYERS; ++layer) {
#pragma unroll
        for (int i = 0; i < NQ; ++i) RY(dc[i], dsn[i], i);
#pragma unroll
        for (int i = 0; i < NQ; ++i) {
            int t4 = (layer * NQ + i) * 4;
            float cy = trig[t4 + 0], sy = trig[t4 + 1];
            float cz = trig[t4 + 2], sz = trig[t4 + 3];
            RY(cy, sy, i);
            RZ(cz, sz, i);
        }
        int shift = layer + 1;
#pragma unroll
        for (int i = 0; i < NQ; ++i) CNOT(i, (i + shift) % NQ);
    }

    float p0 = a0r * a0r + a0i * a0i;
    float p1 = a1r * a1r + a1i * a1i;
    float tp = p0 + p1;
    float tm = p0 - p1;

    // Walsh-Hadamard over the 6 lane bits
#pragma unroll
    for (int s = 0; s < 6; ++s) {
        int m = 1 << s;
        float pp = __shfl_xor(tp, m, 64);
        float pm = __shfl_xor(tm, m, 64);
        tp = (lane & m) ? (pp - tp) : (tp + pp);
        tm = (lane & m) ? (pm - tm) : (tm + pm);
    }

    float* qo = q_out + (size_t)wave * 14;
    int fp = -1;
    switch (lane) {
        case 32: fp = 1;  break;
        case 16: fp = 2;  break;
        case 8:  fp = 3;  break;
        case 4:  fp = 4;  break;
        case 2:  fp = 5;  break;
        case 1:  fp = 6;  break;
        case 48: fp = 8;  break;
        case 24: fp = 9;  break;
        case 12: fp = 10; break;
        case 6:  fp = 11; break;
        case 3:  fp = 12; break;
        default: break;
    }
    if (fp >= 0)    qo[fp] = tp;
    if (lane == 0)  qo[0]  = tm;
    if (lane == 32) qo[7]  = tm;
    if (lane == 1)  qo[13] = tm;
}

// ---------------------------------------------------------------------------
// Fused MLP (encoder + fusion): block = 256 threads (4 waves) = 64 rows.
// lane = row within tile; each wave owns a column slice per layer.
// Activations transposed in LDS [k][row]; weight reads wave-uniform -> s_load.
//
// LDS plan (61.4 KB, 2 blocks/CU):
//   A1[110][S1=65] : comb transposed. rows 0..13 q_out, 14..45 c_enc, 46..109 x_c
//                    later reused: rows 0..63 = h2, rows 64..95 = h3
//   A2[128][64]    : h1 transposed. first 64 rows double as encoder-h buffer H.
// ---------------------------------------------------------------------------
__global__ __launch_bounds__(256) void mlp_kernel(
    const float* __restrict__ q_out, const float* __restrict__ x_c,
    const float* __restrict__ ew1, const float* __restrict__ eb1,
    const float* __restrict__ ew2, const float* __restrict__ eb2,
    const float* __restrict__ w1,  const float* __restrict__ b1,
    const float* __restrict__ w2,  const float* __restrict__ b2,
    const float* __restrict__ w3,  const float* __restrict__ b3,
    const float* __restrict__ w4,  const float* __restrict__ b4,
    float* __restrict__ out, int B)
{
    __shared__ float A1[110 * S1];
    __shared__ float A2[128 * 64];

    const int tid  = threadIdx.x;
    const int lane = tid & 63;
    const int wv   = __builtin_amdgcn_readfirstlane(tid >> 6);
    const int base = blockIdx.x * ROWS;

    // ---- stage x_c -> A1[46+k][r] (coalesced reads, pad-65 kills bank conflict)
    for (int idx = tid; idx < 64 * 64; idx += 256) {
        int r = idx >> 6, k = idx & 63;
        A1[(46 + k) * S1 + r] = x_c[(size_t)(base + r) * 64 + k];
    }
    // ---- stage q_out -> A1[k][r]
    for (int idx = tid; idx < 64 * 14; idx += 256) {
        int r = idx / 14, k = idx - r * 14;
        A1[k * S1 + r] = q_out[(size_t)(base + r) * 14 + k];
    }
    __syncthreads();

    // ---- encoder L1: h = relu(x @ ew1 + eb1), 64 cols -> 16/wave. H = A2[0..63]
    {
        const int cb = wv * 16;
        float acc[16];
#pragma unroll
        for (int j = 0; j < 16; ++j) acc[j] = eb1[cb + j];
#pragma unroll 2
        for (int k = 0; k < 64; ++k) {
            float a = A1[(46 + k) * S1 + lane];
            const float* w = ew1 + k * 64 + cb;
#pragma unroll
            for (int j = 0; j < 16; ++j) acc[j] = fmaf(a, w[j], acc[j]);
        }
#pragma unroll
        for (int j = 0; j < 16; ++j)
            A2[(cb + j) * 64 + lane] = fmaxf(acc[j], 0.0f);
    }
    __syncthreads();

    // ---- encoder L2: c_enc = relu(h @ ew2 + eb2), 32 cols -> 8/wave
    {
        const int cb = wv * 8;
        float acc[8];
#pragma unroll
        for (int j = 0; j < 8; ++j) acc[j] = eb2[cb + j];
#pragma unroll 2
        for (int k = 0; k < 64; ++k) {
            float a = A2[k * 64 + lane];
            const float* w = ew2 + k * 32 + cb;
#pragma unroll
            for (int j = 0; j < 8; ++j) acc[j] = fmaf(a, w[j], acc[j]);
        }
#pragma unroll
        for (int j = 0; j < 8; ++j)
            A1[(14 + cb + j) * S1 + lane] = fmaxf(acc[j], 0.0f);
    }
    __syncthreads();

    // ---- fusion L1: h1 = relu(comb @ w1 + b1), 128 cols -> 32/wave, K=110
    {
        const int cb = wv * 32;
        float acc[32];
#pragma unroll
        for (int j = 0; j < 32; ++j) acc[j] = b1[cb + j];
#pragma unroll 2
        for (int k = 0; k < 110; ++k) {
            float a = A1[k * S1 + lane];
            const float* w = w1 + k * 128 + cb;
#pragma unroll
            for (int j = 0; j < 32; ++j) acc[j] = fmaf(a, w[j], acc[j]);
        }
#pragma unroll
        for (int j = 0; j < 32; ++j)
            A2[(cb + j) * 64 + lane] = fmaxf(acc[j], 0.0f);
    }
    __syncthreads();

    // ---- fusion L2: h2 = relu(h1 @ w2 + b2), 64 cols -> 16/wave, K=128
    // output to A1 rows 0..63 (comb is dead now)
    {
        const int cb = wv * 16;
        float acc[16];
#pragma unroll
        for (int j = 0; j < 16; ++j) acc[j] = b2[cb + j];
#pragma unroll 2
        for (int k = 0; k < 128; ++k) {
            float a = A2[k * 64 + lane];
            const float* w = w2 + k * 64 + cb;
#pragma unroll
            for (int j = 0; j < 16; ++j) acc[j] = fmaf(a, w[j], acc[j]);
        }
#pragma unroll
        for (int j = 0; j < 16; ++j)
            A1[(cb + j) * S1 + lane] = fmaxf(acc[j], 0.0f);
    }
    __syncthreads();

    // ---- fusion L3: h3 = relu(h2 @ w3 + b3), 32 cols -> 8/wave, K=64
    // reads A1 rows 0..63, writes A1 rows 64..95 (disjoint)
    {
        const int cb = wv * 8;
        float acc[8];
#pragma unroll
        for (int j = 0; j < 8; ++j) acc[j] = b3[cb + j];
#pragma unroll 2
        for (int k = 0; k < 64; ++k) {
            float a = A1[k * S1 + lane];
            const float* w = w3 + k * 32 + cb;
#pragma unroll
            for (int j = 0; j < 8; ++j) acc[j] = fmaf(a, w[j], acc[j]);
        }
#pragma unroll
        for (int j = 0; j < 8; ++j)
            A1[(64 + cb + j) * S1 + lane] = fmaxf(acc[j], 0.0f);
    }
    __syncthreads();

    // ---- fusion L4: out = h3 @ w4 + b4 (1 col), wave 0 only
    if (wv == 0) {
        float acc = b4[0];
#pragma unroll
        for (int k = 0; k < 32; ++k)
            acc = fmaf(A1[(64 + k) * S1 + lane], w4[k], acc);
        out[base + lane] = acc;
    }
}

// ---------------------------------------------------------------------------
extern "C" void kernel_launch(void* const* d_in, const int* in_sizes, int n_in,
                              void* d_out, int out_size, void* d_ws, size_t ws_size,
                              hipStream_t stream)
{
    const float* x_q     = (const float*)d_in[0];
    const float* x_c     = (const float*)d_in[1];
    const float* scales  = (const float*)d_in[2];
    const float* biases  = (const float*)d_in[3];
    const float* wry     = (const float*)d_in[4];
    const float* wrz     = (const float*)d_in[5];
    const float* enc_w1  = (const float*)d_in[6];
    const float* enc_b1  = (const float*)d_in[7];
    const float* enc_w2  = (const float*)d_in[8];
    const float* enc_b2  = (const float*)d_in[9];
    const float* fus_w1  = (const float*)d_in[10];
    const float* fus_b1  = (const float*)d_in[11];
    const float* fus_w2  = (const float*)d_in[12];
    const float* fus_b2  = (const float*)d_in[13];
    const float* fus_w3  = (const float*)d_in[14];
    const float* fus_b3  = (const float*)d_in[15];
    const float* fus_w4  = (const float*)d_in[16];
    const float* fus_b4  = (const float*)d_in[17];
    float* out = (float*)d_out;

    int B = in_sizes[0] / NQ;   // 32768

    // workspace layout (floats)
    float* ws    = (float*)d_ws;
    float* q_out = ws;                          // B*14
    float* trig  = ws + (size_t)B * 14;         // 3*7*4

    precompute_kernel<<<1, 64, 0, stream>>>(wry, wrz, trig);

    int circ_blocks = (B * 64 + 255) / 256;
    circuit_kernel<<<circ_blocks, 256, 0, stream>>>(x_q, scales, biases, trig,
                                                    q_out, B);

    int row_blocks = B / ROWS;   // 512
    mlp_kernel<<<row_blocks, 256, 0, stream>>>(q_out, x_c,
                                               enc_w1, enc_b1, enc_w2, enc_b2,
                                               fus_w1, fus_b1, fus_w2, fus_b2,
                                               fus_w3, fus_b3, fus_w4, fus_b4,
                                               out, B);
}

// Round 3
// 97.695 us; speedup vs baseline: 3.1597x; 1.2664x over previous
//
#include <hip/hip_runtime.h>
#include <math.h>

#define NQ 7
#define DIM 128
#define NLAYERS 3
#define ROWS 64
#define S1 65   // padded row stride of A1

// ---------------------------------------------------------------------------
// Compile-time composition of a layer's 7 CNOTs into one linear gather map.
// Reference: new[k] = old[perm(k)], perm(k) = k ^ (((k>>(6-c))&1)<<(6-t)).
// Gates applied i=0..6 -> composite gather g(k) = p0(p1(...p6(k))).
// g is GF(2)-linear; GCOL(L,j) = g(1<<j) for layer L (shift = L+1).
// ---------------------------------------------------------------------------
constexpr int cperm(int k, int c, int t) {
    return k ^ (((k >> (6 - c)) & 1) << (6 - t));
}
constexpr int lgather(int k, int s) {
    int r = k;
    for (int i = 6; i >= 0; --i) r = cperm(r, i, (i + s) % 7);
    return r;
}
constexpr int GCOL(int L, int j) { return lgather(1 << j, L + 1); }
// the 2-fetch gather scheme requires bit6 to toggle between src0 and src1:
static_assert((lgather(64, 1) & 64) && (lgather(64, 2) & 64) && (lgather(64, 3) & 64),
              "bit6 of C6 must be set for all layers");

__device__ __forceinline__ float bpermf(int addr, float v) {
    return __int_as_float(__builtin_amdgcn_ds_bpermute(addr, __float_as_int(v)));
}

// ---------------------------------------------------------------------------
// Precompute: trig table for weight-RY angles (batch-uniform)
// trig[(l*NQ+i)*2 + {0,1}] = cos(wry/2), sin(wry/2)
// ---------------------------------------------------------------------------
__global__ __launch_bounds__(64) void precompute_kernel(
    const float* __restrict__ wry, float* __restrict__ trig)
{
    int tid = threadIdx.x;
    if (tid < NLAYERS * NQ) {
        float hy = 0.5f * wry[tid];
        trig[tid * 2 + 0] = cosf(hy);
        trig[tid * 2 + 1] = sinf(hy);
    }
}

// ---------------------------------------------------------------------------
// Quantum circuit: one wave per batch element; lane holds amps (lane, lane+64).
// Qubit q acts on state bit p = 6-q.
//  - layer-0 data-RY block folded into closed-form product state (real)
//  - per-layer RZs merged into one diagonal phase (commute across qubits)
//  - per-layer CNOT block composed into one linear gather (4 ds_bpermute)
//  - hardware trig (v_sin/v_cos) for data angles + RZ phases
// ---------------------------------------------------------------------------
__global__ __launch_bounds__(256) void circuit_kernel(
    const float* __restrict__ x_q, const float* __restrict__ scales,
    const float* __restrict__ biases, const float* __restrict__ trig,
    const float* __restrict__ wrz,
    float* __restrict__ q_out, int B)
{
    int gtid = blockIdx.x * blockDim.x + threadIdx.x;
    int wave = gtid >> 6;
    int lane = threadIdx.x & 63;
    if (wave >= B) return;

    // Data-angle trig (reused across layers) — hardware sin/cos
    float dc[NQ], dsn[NQ];
#pragma unroll
    for (int i = 0; i < NQ; ++i) {
        float h = 0.5f * fmaf(scales[i], x_q[wave * NQ + i], biases[i]);
        dc[i]  = __cosf(h);
        dsn[i] = __sinf(h);
    }

    // ---- layer-0 data-RY block on |0...0>: product state (real)
    // qubit q <-> lane bit (6-q); bit set -> sin factor
    float pr;
    {
        float f1 = (lane & 32) ? dsn[1] : dc[1];
        float f2 = (lane & 16) ? dsn[2] : dc[2];
        float f3 = (lane &  8) ? dsn[3] : dc[3];
        float f4 = (lane &  4) ? dsn[4] : dc[4];
        float f5 = (lane &  2) ? dsn[5] : dc[5];
        float f6 = (lane &  1) ? dsn[6] : dc[6];
        pr = (f1 * f2) * (f3 * f4) * (f5 * f6);
    }
    float a0r = pr * dc[0], a0i = 0.0f;
    float a1r = pr * dsn[0], a1i = 0.0f;

    auto RY = [&](float c, float s, int q) {
        int p = 6 - q;
        if (p == 6) {
            float n0r = c * a0r - s * a1r;
            float n0i = c * a0i - s * a1i;
            float n1r = s * a0r + c * a1r;
            float n1i = s * a0i + c * a1i;
            a0r = n0r; a0i = n0i; a1r = n1r; a1i = n1i;
        } else {
            int m = 1 << p;
            float sg = (lane & m) ? s : -s;
            float p0r = __shfl_xor(a0r, m, 64);
            float p0i = __shfl_xor(a0i, m, 64);
            float p1r = __shfl_xor(a1r, m, 64);
            float p1i = __shfl_xor(a1i, m, 64);
            a0r = fmaf(c, a0r, sg * p0r);
            a0i = fmaf(c, a0i, sg * p0i);
            a1r = fmaf(c, a1r, sg * p1r);
            a1i = fmaf(c, a1i, sg * p1i);
        }
    };

#pragma unroll
    for (int layer = 0; layer < NLAYERS; ++layer) {
        // ---- data RY block (layer 0's is folded into the init product)
        if (layer > 0) {
#pragma unroll
            for (int i = 0; i < NQ; ++i) RY(dc[i], dsn[i], i);
        }

        // ---- weight RY block (RZs commute past later RYs on other qubits)
#pragma unroll
        for (int i = 0; i < NQ; ++i) {
            int t2 = (layer * NQ + i) * 2;
            RY(trig[t2 + 0], trig[t2 + 1], i);
        }

        // ---- merged RZ: amp k *= exp(-0.5i * sum_q sigma_q(k) * wrz[l,q])
        {
            float base = 0.0f;
#pragma unroll
            for (int q = 1; q < NQ; ++q) {
                float h = 0.5f * wrz[layer * NQ + q];
                base += (lane & (1 << (6 - q))) ? -h : h;
            }
            float h0  = 0.5f * wrz[layer * NQ];
            float th0 = base + h0;     // a0: bit6 = 0
            float th1 = base - h0;     // a1: bit6 = 1
            float c0 = __cosf(th0), s0 = __sinf(th0);
            float c1 = __cosf(th1), s1 = __sinf(th1);
            float r, im;
            r = a0r; im = a0i;
            a0r = fmaf(c0, r, s0 * im);
            a0i = fmaf(c0, im, -s0 * r);
            r = a1r; im = a1i;
            a1r = fmaf(c1, r, s1 * im);
            a1i = fmaf(c1, im, -s1 * r);
        }

        // ---- composed CNOT block: new[k] = old[g(k)], g linear over GF(2)
        {
            int s0 = 0;
#pragma unroll
            for (int j = 0; j < 6; ++j)
                s0 ^= (lane & (1 << j)) ? GCOL(layer, j) : 0;
            const int c6 = GCOL(layer, 6);
            int s1x = s0 ^ c6;
            int l0 = (s0 & 63) << 2, l1 = (s1x & 63) << 2;
            bool f0 = (s0 & 64) != 0;
            int aP0 = f0 ? l1 : l0;   // lane to fetch from plane a0
            int aP1 = f0 ? l0 : l1;   // lane to fetch from plane a1
            float g0, g1;
            g0 = bpermf(aP0, a0r); g1 = bpermf(aP1, a1r);
            a0r = f0 ? g1 : g0;  a1r = f0 ? g0 : g1;
            g0 = bpermf(aP0, a0i); g1 = bpermf(aP1, a1i);
            a0i = f0 ? g1 : g0;  a1i = f0 ? g0 : g1;
        }
    }

    float p0 = a0r * a0r + a0i * a0i;
    float p1 = a1r * a1r + a1i * a1i;
    float tp = p0 + p1;
    float tm = p0 - p1;

    // Walsh-Hadamard over the 6 lane bits
#pragma unroll
    for (int s = 0; s < 6; ++s) {
        int m = 1 << s;
        float pp = __shfl_xor(tp, m, 64);
        float pm = __shfl_xor(tm, m, 64);
        tp = (lane & m) ? (pp - tp) : (tp + pp);
        tm = (lane & m) ? (pm - tm) : (tm + pm);
    }

    float* qo = q_out + (size_t)wave * 14;
    int fp = -1;
    switch (lane) {
        case 32: fp = 1;  break;
        case 16: fp = 2;  break;
        case 8:  fp = 3;  break;
        case 4:  fp = 4;  break;
        case 2:  fp = 5;  break;
        case 1:  fp = 6;  break;
        case 48: fp = 8;  break;
        case 24: fp = 9;  break;
        case 12: fp = 10; break;
        case 6:  fp = 11; break;
        case 3:  fp = 12; break;
        default: break;
    }
    if (fp >= 0)    qo[fp] = tp;
    if (lane == 0)  qo[0]  = tm;
    if (lane == 32) qo[7]  = tm;
    if (lane == 1)  qo[13] = tm;
}

// ---------------------------------------------------------------------------
// Fused MLP (encoder + fusion): block = 256 threads (4 waves) = 64 rows.
// ---------------------------------------------------------------------------
__global__ __launch_bounds__(256) void mlp_kernel(
    const float* __restrict__ q_out, const float* __restrict__ x_c,
    const float* __restrict__ ew1, const float* __restrict__ eb1,
    const float* __restrict__ ew2, const float* __restrict__ eb2,
    const float* __restrict__ w1,  const float* __restrict__ b1,
    const float* __restrict__ w2,  const float* __restrict__ b2,
    const float* __restrict__ w3,  const float* __restrict__ b3,
    const float* __restrict__ w4,  const float* __restrict__ b4,
    float* __restrict__ out, int B)
{
    __shared__ float A1[110 * S1];
    __shared__ float A2[128 * 64];

    const int tid  = threadIdx.x;
    const int lane = tid & 63;
    const int wv   = __builtin_amdgcn_readfirstlane(tid >> 6);
    const int base = blockIdx.x * ROWS;

    for (int idx = tid; idx < 64 * 64; idx += 256) {
        int r = idx >> 6, k = idx & 63;
        A1[(46 + k) * S1 + r] = x_c[(size_t)(base + r) * 64 + k];
    }
    for (int idx = tid; idx < 64 * 14; idx += 256) {
        int r = idx / 14, k = idx - r * 14;
        A1[k * S1 + r] = q_out[(size_t)(base + r) * 14 + k];
    }
    __syncthreads();

    // ---- encoder L1
    {
        const int cb = wv * 16;
        float acc[16];
#pragma unroll
        for (int j = 0; j < 16; ++j) acc[j] = eb1[cb + j];
#pragma unroll 2
        for (int k = 0; k < 64; ++k) {
            float a = A1[(46 + k) * S1 + lane];
            const float* w = ew1 + k * 64 + cb;
#pragma unroll
            for (int j = 0; j < 16; ++j) acc[j] = fmaf(a, w[j], acc[j]);
        }
#pragma unroll
        for (int j = 0; j < 16; ++j)
            A2[(cb + j) * 64 + lane] = fmaxf(acc[j], 0.0f);
    }
    __syncthreads();

    // ---- encoder L2
    {
        const int cb = wv * 8;
        float acc[8];
#pragma unroll
        for (int j = 0; j < 8; ++j) acc[j] = eb2[cb + j];
#pragma unroll 2
        for (int k = 0; k < 64; ++k) {
            float a = A2[k * 64 + lane];
            const float* w = ew2 + k * 32 + cb;
#pragma unroll
            for (int j = 0; j < 8; ++j) acc[j] = fmaf(a, w[j], acc[j]);
        }
#pragma unroll
        for (int j = 0; j < 8; ++j)
            A1[(14 + cb + j) * S1 + lane] = fmaxf(acc[j], 0.0f);
    }
    __syncthreads();

    // ---- fusion L1 (K=110)
    {
        const int cb = wv * 32;
        float acc[32];
#pragma unroll
        for (int j = 0; j < 32; ++j) acc[j] = b1[cb + j];
#pragma unroll 2
        for (int k = 0; k < 110; ++k) {
            float a = A1[k * S1 + lane];
            const float* w = w1 + k * 128 + cb;
#pragma unroll
            for (int j = 0; j < 32; ++j) acc[j] = fmaf(a, w[j], acc[j]);
        }
#pragma unroll
        for (int j = 0; j < 32; ++j)
            A2[(cb + j) * 64 + lane] = fmaxf(acc[j], 0.0f);
    }
    __syncthreads();

    // ---- fusion L2 (K=128)
    {
        const int cb = wv * 16;
        float acc[16];
#pragma unroll
        for (int j = 0; j < 16; ++j) acc[j] = b2[cb + j];
#pragma unroll 2
        for (int k = 0; k < 128; ++k) {
            float a = A2[k * 64 + lane];
            const float* w = w2 + k * 64 + cb;
#pragma unroll
            for (int j = 0; j < 16; ++j) acc[j] = fmaf(a, w[j], acc[j]);
        }
#pragma unroll
        for (int j = 0; j < 16; ++j)
            A1[(cb + j) * S1 + lane] = fmaxf(acc[j], 0.0f);
    }
    __syncthreads();

    // ---- fusion L3 (K=64)
    {
        const int cb = wv * 8;
        float acc[8];
#pragma unroll
        for (int j = 0; j < 8; ++j) acc[j] = b3[cb + j];
#pragma unroll 2
        for (int k = 0; k < 64; ++k) {
            float a = A1[k * S1 + lane];
            const float* w = w3 + k * 32 + cb;
#pragma unroll
            for (int j = 0; j < 8; ++j) acc[j] = fmaf(a, w[j], acc[j]);
        }
#pragma unroll
        for (int j = 0; j < 8; ++j)
            A1[(64 + cb + j) * S1 + lane] = fmaxf(acc[j], 0.0f);
    }
    __syncthreads();

    // ---- fusion L4 (1 col)
    if (wv == 0) {
        float acc = b4[0];
#pragma unroll
        for (int k = 0; k < 32; ++k)
            acc = fmaf(A1[(64 + k) * S1 + lane], w4[k], acc);
        out[base + lane] = acc;
    }
}

// ---------------------------------------------------------------------------
extern "C" void kernel_launch(void* const* d_in, const int* in_sizes, int n_in,
                              void* d_out, int out_size, void* d_ws, size_t ws_size,
                              hipStream_t stream)
{
    const float* x_q     = (const float*)d_in[0];
    const float* x_c     = (const float*)d_in[1];
    const float* scales  = (const float*)d_in[2];
    const float* biases  = (const float*)d_in[3];
    const float* wry     = (const float*)d_in[4];
    const float* wrz     = (const float*)d_in[5];
    const float* enc_w1  = (const float*)d_in[6];
    const float* enc_b1  = (const float*)d_in[7];
    const float* enc_w2  = (const float*)d_in[8];
    const float* enc_b2  = (const float*)d_in[9];
    const float* fus_w1  = (const float*)d_in[10];
    const float* fus_b1  = (const float*)d_in[11];
    const float* fus_w2  = (const float*)d_in[12];
    const float* fus_b2  = (const float*)d_in[13];
    const float* fus_w3  = (const float*)d_in[14];
    const float* fus_b3  = (const float*)d_in[15];
    const float* fus_w4  = (const float*)d_in[16];
    const float* fus_b4  = (const float*)d_in[17];
    float* out = (float*)d_out;

    int B = in_sizes[0] / NQ;   // 32768

    // workspace layout (floats)
    float* ws    = (float*)d_ws;
    float* q_out = ws;                          // B*14
    float* trig  = ws + (size_t)B * 14;         // 3*7*2

    precompute_kernel<<<1, 64, 0, stream>>>(wry, trig);

    int circ_blocks = (B * 64 + 255) / 256;
    circuit_kernel<<<circ_blocks, 256, 0, stream>>>(x_q, scales, biases, trig,
                                                    wrz, q_out, B);

    int row_blocks = B / ROWS;   // 512
    mlp_kernel<<<row_blocks, 256, 0, stream>>>(q_out, x_c,
                                               enc_w1, enc_b1, enc_w2, enc_b2,
                                               fus_w1, fus_b1, fus_w2, fus_b2,
                                               fus_w3, fus_b3, fus_w4, fus_b4,
                                               out, B);
}

// Round 4
// 84.943 us; speedup vs baseline: 3.6341x; 1.1501x over previous
//
#include <hip/hip_runtime.h>
#include <math.h>

#define NQ 7
#define DIM 128
#define NLAYERS 3
#define ROWS 64
#define LDS_S 136   // LDS row stride in bf16 units: 272 B = 17*16B (aligned b128, 2-way banks)

typedef __attribute__((ext_vector_type(8))) short bf16x8;
typedef __attribute__((ext_vector_type(4))) float f32x4;
typedef __attribute__((ext_vector_type(4))) unsigned short us4;

__device__ __forceinline__ unsigned short f2bf(float x) {
    union { float f; unsigned int u; } v; v.f = x;
    unsigned int r = v.u + 0x7fff + ((v.u >> 16) & 1);   // RNE
    return (unsigned short)(r >> 16);
}

// ---------------------------------------------------------------------------
// Compile-time composition of a layer's 7 CNOTs into one linear gather map.
// ---------------------------------------------------------------------------
constexpr int cperm(int k, int c, int t) {
    return k ^ (((k >> (6 - c)) & 1) << (6 - t));
}
constexpr int lgather(int k, int s) {
    int r = k;
    for (int i = 6; i >= 0; --i) r = cperm(r, i, (i + s) % 7);
    return r;
}
constexpr int GCOL(int L, int j) { return lgather(1 << j, L + 1); }
static_assert((lgather(64, 1) & 64) && (lgather(64, 2) & 64) && (lgather(64, 3) & 64),
              "bit6 of C6 must be set for all layers");

__device__ __forceinline__ float bpermf(int addr, float v) {
    return __int_as_float(__builtin_amdgcn_ds_bpermute(addr, __float_as_int(v)));
}

// ---------------------------------------------------------------------------
// Precompute: circuit trig + all MLP weights transposed to [N][Kp] bf16.
// w1t K-permutation: k' 0-63 = x_c rows (46..109), 64-77 = q rows (0..13),
//                    78-109 = c_enc rows (14..45), 110-127 = zero pad.
// ---------------------------------------------------------------------------
__global__ __launch_bounds__(256) void precompute_kernel(
    const float* __restrict__ wry,
    const float* __restrict__ ew1, const float* __restrict__ ew2,
    const float* __restrict__ w1,  const float* __restrict__ w2,
    const float* __restrict__ w3,  const float* __restrict__ w4,
    float* __restrict__ trig,
    unsigned short* __restrict__ ew1t, unsigned short* __restrict__ ew2t,
    unsigned short* __restrict__ w1t,  unsigned short* __restrict__ w2t,
    unsigned short* __restrict__ w3t,  unsigned short* __restrict__ w4t)
{
    int tid = threadIdx.x;
    if (tid < NLAYERS * NQ) {
        float hy = 0.5f * wry[tid];
        trig[tid * 2 + 0] = cosf(hy);
        trig[tid * 2 + 1] = sinf(hy);
    }
    // ew1t[n*64+k] = ew1[k*64+n]        (64x64)
    for (int i = tid; i < 4096; i += 256) {
        int n = i >> 6, k = i & 63;
        ew1t[i] = f2bf(ew1[k * 64 + n]);
    }
    // ew2t[n*64+k] = ew2[k*32+n]        (32x64)
    for (int i = tid; i < 2048; i += 256) {
        int n = i >> 6, k = i & 63;
        ew2t[i] = f2bf(ew2[k * 32 + n]);
    }
    // w1t[n*128+kp], permuted K         (128x128)
    for (int i = tid; i < 16384; i += 256) {
        int n = i >> 7, kp = i & 127;
        unsigned short v = 0;
        if (kp < 64)        v = f2bf(w1[(46 + kp) * 128 + n]);
        else if (kp < 78)   v = f2bf(w1[(kp - 64) * 128 + n]);
        else if (kp < 110)  v = f2bf(w1[(kp - 78 + 14) * 128 + n]);
        w1t[i] = v;
    }
    // w2t[n*128+k] = w2[k*64+n]         (64x128)
    for (int i = tid; i < 8192; i += 256) {
        int n = i >> 7, k = i & 127;
        w2t[i] = f2bf(w2[k * 64 + n]);
    }
    // w3t[n*64+k] = w3[k*32+n]          (32x64)
    for (int i = tid; i < 2048; i += 256) {
        int n = i >> 6, k = i & 63;
        w3t[i] = f2bf(w3[k * 32 + n]);
    }
    // w4t[n*32+k]: row 0 = w4, rows 1-15 zero   (16x32)
    for (int i = tid; i < 512; i += 256) {
        int n = i >> 5, k = i & 31;
        w4t[i] = (n == 0) ? f2bf(w4[k]) : (unsigned short)0;
    }
}

// ---------------------------------------------------------------------------
// Quantum circuit: one wave per batch element (unchanged, verified).
// ---------------------------------------------------------------------------
__global__ __launch_bounds__(256) void circuit_kernel(
    const float* __restrict__ x_q, const float* __restrict__ scales,
    const float* __restrict__ biases, const float* __restrict__ trig,
    const float* __restrict__ wrz,
    float* __restrict__ q_out, int B)
{
    int gtid = blockIdx.x * blockDim.x + threadIdx.x;
    int wave = gtid >> 6;
    int lane = threadIdx.x & 63;
    if (wave >= B) return;

    float dc[NQ], dsn[NQ];
#pragma unroll
    for (int i = 0; i < NQ; ++i) {
        float h = 0.5f * fmaf(scales[i], x_q[wave * NQ + i], biases[i]);
        dc[i]  = __cosf(h);
        dsn[i] = __sinf(h);
    }

    float pr;
    {
        float f1 = (lane & 32) ? dsn[1] : dc[1];
        float f2 = (lane & 16) ? dsn[2] : dc[2];
        float f3 = (lane &  8) ? dsn[3] : dc[3];
        float f4 = (lane &  4) ? dsn[4] : dc[4];
        float f5 = (lane &  2) ? dsn[5] : dc[5];
        float f6 = (lane &  1) ? dsn[6] : dc[6];
        pr = (f1 * f2) * (f3 * f4) * (f5 * f6);
    }
    float a0r = pr * dc[0], a0i = 0.0f;
    float a1r = pr * dsn[0], a1i = 0.0f;

    auto RY = [&](float c, float s, int q) {
        int p = 6 - q;
        if (p == 6) {
            float n0r = c * a0r - s * a1r;
            float n0i = c * a0i - s * a1i;
            float n1r = s * a0r + c * a1r;
            float n1i = s * a0i + c * a1i;
            a0r = n0r; a0i = n0i; a1r = n1r; a1i = n1i;
        } else {
            int m = 1 << p;
            float sg = (lane & m) ? s : -s;
            float p0r = __shfl_xor(a0r, m, 64);
            float p0i = __shfl_xor(a0i, m, 64);
            float p1r = __shfl_xor(a1r, m, 64);
            float p1i = __shfl_xor(a1i, m, 64);
            a0r = fmaf(c, a0r, sg * p0r);
            a0i = fmaf(c, a0i, sg * p0i);
            a1r = fmaf(c, a1r, sg * p1r);
            a1i = fmaf(c, a1i, sg * p1i);
        }
    };

#pragma unroll
    for (int layer = 0; layer < NLAYERS; ++layer) {
        if (layer > 0) {
#pragma unroll
            for (int i = 0; i < NQ; ++i) RY(dc[i], dsn[i], i);
        }
#pragma unroll
        for (int i = 0; i < NQ; ++i) {
            int t2 = (layer * NQ + i) * 2;
            RY(trig[t2 + 0], trig[t2 + 1], i);
        }
        {
            float base = 0.0f;
#pragma unroll
            for (int q = 1; q < NQ; ++q) {
                float h = 0.5f * wrz[layer * NQ + q];
                base += (lane & (1 << (6 - q))) ? -h : h;
            }
            float h0  = 0.5f * wrz[layer * NQ];
            float th0 = base + h0;
            float th1 = base - h0;
            float c0 = __cosf(th0), s0 = __sinf(th0);
            float c1 = __cosf(th1), s1 = __sinf(th1);
            float r, im;
            r = a0r; im = a0i;
            a0r = fmaf(c0, r, s0 * im);
            a0i = fmaf(c0, im, -s0 * r);
            r = a1r; im = a1i;
            a1r = fmaf(c1, r, s1 * im);
            a1i = fmaf(c1, im, -s1 * r);
        }
        {
            int s0 = 0;
#pragma unroll
            for (int j = 0; j < 6; ++j)
                s0 ^= (lane & (1 << j)) ? GCOL(layer, j) : 0;
            const int c6 = GCOL(layer, 6);
            int s1x = s0 ^ c6;
            int l0 = (s0 & 63) << 2, l1 = (s1x & 63) << 2;
            bool f0 = (s0 & 64) != 0;
            int aP0 = f0 ? l1 : l0;
            int aP1 = f0 ? l0 : l1;
            float g0, g1;
            g0 = bpermf(aP0, a0r); g1 = bpermf(aP1, a1r);
            a0r = f0 ? g1 : g0;  a1r = f0 ? g0 : g1;
            g0 = bpermf(aP0, a0i); g1 = bpermf(aP1, a1i);
            a0i = f0 ? g1 : g0;  a1i = f0 ? g0 : g1;
        }
    }

    float p0 = a0r * a0r + a0i * a0i;
    float p1 = a1r * a1r + a1i * a1i;
    float tp = p0 + p1;
    float tm = p0 - p1;

#pragma unroll
    for (int s = 0; s < 6; ++s) {
        int m = 1 << s;
        float pp = __shfl_xor(tp, m, 64);
        float pm = __shfl_xor(tm, m, 64);
        tp = (lane & m) ? (pp - tp) : (tp + pp);
        tm = (lane & m) ? (pm - tm) : (tm + pm);
    }

    float* qo = q_out + (size_t)wave * 14;
    int fp = -1;
    switch (lane) {
        case 32: fp = 1;  break;
        case 16: fp = 2;  break;
        case 8:  fp = 3;  break;
        case 4:  fp = 4;  break;
        case 2:  fp = 5;  break;
        case 1:  fp = 6;  break;
        case 48: fp = 8;  break;
        case 24: fp = 9;  break;
        case 12: fp = 10; break;
        case 6:  fp = 11; break;
        case 3:  fp = 12; break;
        default: break;
    }
    if (fp >= 0)    qo[fp] = tp;
    if (lane == 0)  qo[0]  = tm;
    if (lane == 32) qo[7]  = tm;
    if (lane == 1)  qo[13] = tm;
}

// ---------------------------------------------------------------------------
// One MFMA layer: Y[64][N] = act(X[64][K] @ Wt^T + b) into LDS (bf16).
//   src/dst: LDS, row stride LDS_S. wt: global [N][K] bf16. K mult of 32.
//   Tile split: 4 mtiles x NTILES ntiles over 4 waves, A-frags reused
//   across a wave's ntiles.
// Frag layouts (m89/m92-verified): A/B lane l holds 8 contiguous K elems at
//   (m|n) = l&15, k = kb*32 + (l>>4)*8; D elem r at row (l>>4)*4+r, col l&15.
// ---------------------------------------------------------------------------
template<int K, int NTILES, bool RELU>
__device__ __forceinline__ void layer_mfma(
    const unsigned short* src, unsigned short* dst,
    const unsigned short* __restrict__ wt, const float* __restrict__ bias,
    int dstcol, int lane, int wv)
{
    constexpr int KB   = K / 32;
    constexpr int NT_W = (NTILES > 4) ? NTILES / 4 : 1;
    constexpr int MT_W = NTILES / NT_W;
    const int ntile0 = (wv * NT_W) % NTILES;
    const int mtile0 = ((wv * NT_W) / NTILES) * MT_W;
    const int lcol = lane & 15;
    const int lrow = lane >> 4;

    bf16x8 bfrag[NT_W][KB];
    float  bb[NT_W];
#pragma unroll
    for (int n = 0; n < NT_W; ++n) {
#pragma unroll
        for (int kb = 0; kb < KB; ++kb)
            bfrag[n][kb] = *(const bf16x8*)&wt[((ntile0 + n) * 16 + lcol) * K + kb * 32 + lrow * 8];
        bb[n] = bias[(ntile0 + n) * 16 + lcol];
    }

#pragma unroll
    for (int m = 0; m < MT_W; ++m) {
        bf16x8 afrag[KB];
#pragma unroll
        for (int kb = 0; kb < KB; ++kb)
            afrag[kb] = *(const bf16x8*)&src[((mtile0 + m) * 16 + lcol) * LDS_S + kb * 32 + lrow * 8];

        f32x4 acc[NT_W];
#pragma unroll
        for (int n = 0; n < NT_W; ++n) acc[n] = (f32x4){bb[n], bb[n], bb[n], bb[n]};
#pragma unroll
        for (int kb = 0; kb < KB; ++kb)
#pragma unroll
            for (int n = 0; n < NT_W; ++n)
                acc[n] = __builtin_amdgcn_mfma_f32_16x16x32_bf16(afrag[kb], bfrag[n][kb], acc[n], 0, 0, 0);

#pragma unroll
        for (int n = 0; n < NT_W; ++n)
#pragma unroll
            for (int r = 0; r < 4; ++r) {
                float v = acc[n][r];
                if (RELU) v = fmaxf(v, 0.0f);
                dst[((mtile0 + m) * 16 + lrow * 4 + r) * LDS_S + dstcol + (ntile0 + n) * 16 + lcol] = f2bf(v);
            }
    }
}

// ---------------------------------------------------------------------------
// Fused MFMA MLP: 64 rows/block, 256 threads (4 waves).
// BufA comb layout (K-permuted to match w1t): cols 0-63 x_c, 64-77 q_out,
// 78-109 c_enc, 110-127 zero.
// ---------------------------------------------------------------------------
__global__ __launch_bounds__(256, 4) void mlp_kernel(
    const float* __restrict__ q_out, const float* __restrict__ x_c,
    const unsigned short* __restrict__ ew1t, const float* __restrict__ eb1,
    const unsigned short* __restrict__ ew2t, const float* __restrict__ eb2,
    const unsigned short* __restrict__ w1t,  const float* __restrict__ b1,
    const unsigned short* __restrict__ w2t,  const float* __restrict__ b2,
    const unsigned short* __restrict__ w3t,  const float* __restrict__ b3,
    const unsigned short* __restrict__ w4t,  const float* __restrict__ b4,
    float* __restrict__ out, int B)
{
    __shared__ unsigned short BufA[ROWS * LDS_S];
    __shared__ unsigned short BufB[ROWS * LDS_S];

    const int tid  = threadIdx.x;
    const int lane = tid & 63;
    const int wv   = __builtin_amdgcn_readfirstlane(tid >> 6);
    const int base = blockIdx.x * ROWS;

    // ---- stage x_c (fp32 -> bf16) into BufA cols 0-63
    {
        const float4* xr = (const float4*)(x_c + (size_t)base * 64);
        for (int i = tid; i < 1024; i += 256) {
            int row = i >> 4, fc = i & 15;
            float4 v = xr[i];
            us4 b;
            b.x = f2bf(v.x); b.y = f2bf(v.y); b.z = f2bf(v.z); b.w = f2bf(v.w);
            *(us4*)&BufA[row * LDS_S + fc * 4] = b;
        }
    }
    // ---- stage q_out into BufA cols 64-77
    for (int i = tid; i < 64 * 14; i += 256) {
        int row = i / 14, k = i - row * 14;
        BufA[row * LDS_S + 64 + k] = f2bf(q_out[(size_t)(base + row) * 14 + k]);
    }
    // ---- zero pad cols 110-127
    for (int i = tid; i < 64 * 18; i += 256) {
        int row = i / 18, k = i - row * 18;
        BufA[row * LDS_S + 110 + k] = 0;
    }
    __syncthreads();

    // ---- encoder L1: h = relu(x_c @ ew1 + eb1)  [K=64, N=64] -> BufB 0-63
    layer_mfma<64, 4, true>(BufA, BufB, ew1t, eb1, 0, lane, wv);
    __syncthreads();
    // ---- encoder L2: c_enc = relu(h @ ew2 + eb2) [K=64, N=32] -> BufA 78-109
    layer_mfma<64, 2, true>(BufB, BufA, ew2t, eb2, 78, lane, wv);
    __syncthreads();
    // ---- fusion L1: h1 = relu(comb @ w1 + b1)   [K=128, N=128] -> BufB 0-127
    layer_mfma<128, 8, true>(BufA, BufB, w1t, b1, 0, lane, wv);
    __syncthreads();
    // ---- fusion L2: h2 = relu(h1 @ w2 + b2)     [K=128, N=64] -> BufA 0-63
    layer_mfma<128, 4, true>(BufB, BufA, w2t, b2, 0, lane, wv);
    __syncthreads();
    // ---- fusion L3: h3 = relu(h2 @ w3 + b3)     [K=64, N=32] -> BufB 0-31
    layer_mfma<64, 2, true>(BufA, BufB, w3t, b3, 0, lane, wv);
    __syncthreads();

    // ---- fusion L4: out = h3 @ w4 + b4          [K=32, N=1(pad 16)]
    {
        const int lcol = lane & 15;
        const int lrow = lane >> 4;
        bf16x8 a = *(const bf16x8*)&BufB[(wv * 16 + lcol) * LDS_S + lrow * 8];
        bf16x8 b = *(const bf16x8*)&w4t[lcol * 32 + lrow * 8];
        float bv = b4[0];
        f32x4 acc = (f32x4){bv, bv, bv, bv};
        acc = __builtin_amdgcn_mfma_f32_16x16x32_bf16(a, b, acc, 0, 0, 0);
        if (lcol == 0) {
            float4 o; o.x = acc[0]; o.y = acc[1]; o.z = acc[2]; o.w = acc[3];
            *(float4*)(out + base + wv * 16 + lrow * 4) = o;
        }
    }
}

// ---------------------------------------------------------------------------
extern "C" void kernel_launch(void* const* d_in, const int* in_sizes, int n_in,
                              void* d_out, int out_size, void* d_ws, size_t ws_size,
                              hipStream_t stream)
{
    const float* x_q     = (const float*)d_in[0];
    const float* x_c     = (const float*)d_in[1];
    const float* scales  = (const float*)d_in[2];
    const float* biases  = (const float*)d_in[3];
    const float* wry     = (const float*)d_in[4];
    const float* wrz     = (const float*)d_in[5];
    const float* enc_w1  = (const float*)d_in[6];
    const float* enc_b1  = (const float*)d_in[7];
    const float* enc_w2  = (const float*)d_in[8];
    const float* enc_b2  = (const float*)d_in[9];
    const float* fus_w1  = (const float*)d_in[10];
    const float* fus_b1  = (const float*)d_in[11];
    const float* fus_w2  = (const float*)d_in[12];
    const float* fus_b2  = (const float*)d_in[13];
    const float* fus_w3  = (const float*)d_in[14];
    const float* fus_b3  = (const float*)d_in[15];
    const float* fus_w4  = (const float*)d_in[16];
    const float* fus_b4  = (const float*)d_in[17];
    float* out = (float*)d_out;

    int B = in_sizes[0] / NQ;   // 32768

    // workspace layout
    float* ws    = (float*)d_ws;
    float* q_out = ws;                              // B*14 floats
    float* trig  = ws + (size_t)B * 14;             // 48 floats (42 used)
    unsigned short* wsh = (unsigned short*)(trig + 48);
    unsigned short* w1t  = wsh;                     // 16384
    unsigned short* w2t  = w1t + 16384;             // 8192
    unsigned short* ew1t = w2t + 8192;              // 4096
    unsigned short* ew2t = ew1t + 4096;             // 2048
    unsigned short* w3t  = ew2t + 2048;             // 2048
    unsigned short* w4t  = w3t + 2048;              // 512

    precompute_kernel<<<1, 256, 0, stream>>>(wry, enc_w1, enc_w2,
                                             fus_w1, fus_w2, fus_w3, fus_w4,
                                             trig, ew1t, ew2t, w1t, w2t, w3t, w4t);

    int circ_blocks = (B * 64 + 255) / 256;
    circuit_kernel<<<circ_blocks, 256, 0, stream>>>(x_q, scales, biases, trig,
                                                    wrz, q_out, B);

    int row_blocks = B / ROWS;   // 512
    mlp_kernel<<<row_blocks, 256, 0, stream>>>(q_out, x_c,
                                               ew1t, enc_b1, ew2t, enc_b2,
                                               w1t, fus_b1, w2t, fus_b2,
                                               w3t, fus_b3, w4t, fus_b4,
                                               out, B);
}

// Round 5
// 61.788 us; speedup vs baseline: 4.9960x; 1.3748x over previous
//
#include <hip/hip_runtime.h>
#include <math.h>

#define NQ 7
#define DIM 128
#define NLAYERS 3
#define ROWS 64
#define LDS_S 136   // LDS row stride in bf16 units: 272 B = 17*16B (aligned b128, 2-way banks)

typedef __attribute__((ext_vector_type(8))) short bf16x8;
typedef __attribute__((ext_vector_type(4))) float f32x4;
typedef __attribute__((ext_vector_type(4))) unsigned short us4;

__device__ __forceinline__ unsigned short f2bf(float x) {
    union { float f; unsigned int u; } v; v.f = x;
    unsigned int r = v.u + 0x7fff + ((v.u >> 16) & 1);   // RNE
    return (unsigned short)(r >> 16);
}

// ---------------------------------------------------------------------------
// Compile-time composition of a layer's 7 CNOTs into one linear gather map.
// ---------------------------------------------------------------------------
constexpr int cperm(int k, int c, int t) {
    return k ^ (((k >> (6 - c)) & 1) << (6 - t));
}
constexpr int lgather(int k, int s) {
    int r = k;
    for (int i = 6; i >= 0; --i) r = cperm(r, i, (i + s) % 7);
    return r;
}
constexpr int GCOL(int L, int j) { return lgather(1 << j, L + 1); }
static_assert((lgather(64, 1) & 64) && (lgather(64, 2) & 64) && (lgather(64, 3) & 64),
              "bit6 of C6 must be set for all layers");

__device__ __forceinline__ float bpermf(int addr, float v) {
    return __int_as_float(__builtin_amdgcn_ds_bpermute(addr, __float_as_int(v)));
}

// ---------------------------------------------------------------------------
// Precompute: circuit trig + all MLP weights transposed to [N][Kp] bf16.
// ---------------------------------------------------------------------------
__global__ __launch_bounds__(256) void precompute_kernel(
    const float* __restrict__ wry,
    const float* __restrict__ ew1, const float* __restrict__ ew2,
    const float* __restrict__ w1,  const float* __restrict__ w2,
    const float* __restrict__ w3,  const float* __restrict__ w4,
    float* __restrict__ trig,
    unsigned short* __restrict__ ew1t, unsigned short* __restrict__ ew2t,
    unsigned short* __restrict__ w1t,  unsigned short* __restrict__ w2t,
    unsigned short* __restrict__ w3t,  unsigned short* __restrict__ w4t)
{
    int tid = threadIdx.x;
    if (tid < NLAYERS * NQ) {
        float hy = 0.5f * wry[tid];
        trig[tid * 2 + 0] = cosf(hy);
        trig[tid * 2 + 1] = sinf(hy);
    }
    for (int i = tid; i < 4096; i += 256) {
        int n = i >> 6, k = i & 63;
        ew1t[i] = f2bf(ew1[k * 64 + n]);
    }
    for (int i = tid; i < 2048; i += 256) {
        int n = i >> 6, k = i & 63;
        ew2t[i] = f2bf(ew2[k * 32 + n]);
    }
    for (int i = tid; i < 16384; i += 256) {
        int n = i >> 7, kp = i & 127;
        unsigned short v = 0;
        if (kp < 64)        v = f2bf(w1[(46 + kp) * 128 + n]);
        else if (kp < 78)   v = f2bf(w1[(kp - 64) * 128 + n]);
        else if (kp < 110)  v = f2bf(w1[(kp - 78 + 14) * 128 + n]);
        w1t[i] = v;
    }
    for (int i = tid; i < 8192; i += 256) {
        int n = i >> 7, k = i & 127;
        w2t[i] = f2bf(w2[k * 64 + n]);
    }
    for (int i = tid; i < 2048; i += 256) {
        int n = i >> 6, k = i & 63;
        w3t[i] = f2bf(w3[k * 32 + n]);
    }
    for (int i = tid; i < 512; i += 256) {
        int n = i >> 5, k = i & 31;
        w4t[i] = (n == 0) ? f2bf(w4[k]) : (unsigned short)0;
    }
}

// ---------------------------------------------------------------------------
// Quantum circuit: one wave per batch element; lane holds amps (lane, lane+64).
// Qubit q acts on state bit p = 6-q.
//  - data-RY and weight-RY on the same qubit merged: RY(a)RY(b)=RY(a+b)
//    (angle-addition on precomputed weight trig, 4 FMA per gate)
//  - layer-0's ENTIRE combined RY block folded into closed-form product state
//  - per-layer RZs merged into one diagonal phase
//  - per-layer CNOT block composed into one linear gather (4 ds_bpermute)
// ---------------------------------------------------------------------------
__global__ __launch_bounds__(256) void circuit_kernel(
    const float* __restrict__ x_q, const float* __restrict__ scales,
    const float* __restrict__ biases, const float* __restrict__ trig,
    const float* __restrict__ wrz,
    float* __restrict__ q_out, int B)
{
    int gtid = blockIdx.x * blockDim.x + threadIdx.x;
    int wave = gtid >> 6;
    int lane = threadIdx.x & 63;
    if (wave >= B) return;

    // data half-angle trig (hardware sin/cos; reused across layers)
    float dc[NQ], dsn[NQ];
#pragma unroll
    for (int i = 0; i < NQ; ++i) {
        float h = 0.5f * fmaf(scales[i], x_q[wave * NQ + i], biases[i]);
        dc[i]  = __cosf(h);
        dsn[i] = __sinf(h);
    }

    // ---- layer-0 combined (data+weight) RY block on |0...0>: product state
    float a0r, a0i = 0.0f, a1r, a1i = 0.0f;
    {
        float cl[NQ], sl[NQ];
#pragma unroll
        for (int i = 0; i < NQ; ++i) {
            float cw = trig[i * 2 + 0], sw = trig[i * 2 + 1];
            cl[i] = dc[i] * cw - dsn[i] * sw;
            sl[i] = dsn[i] * cw + dc[i] * sw;
        }
        float f1 = (lane & 32) ? sl[1] : cl[1];
        float f2 = (lane & 16) ? sl[2] : cl[2];
        float f3 = (lane &  8) ? sl[3] : cl[3];
        float f4 = (lane &  4) ? sl[4] : cl[4];
        float f5 = (lane &  2) ? sl[5] : cl[5];
        float f6 = (lane &  1) ? sl[6] : cl[6];
        float pr = (f1 * f2) * (f3 * f4) * (f5 * f6);
        a0r = pr * cl[0];
        a1r = pr * sl[0];
    }

    auto RY = [&](float c, float s, int q) {
        int p = 6 - q;
        if (p == 6) {
            float n0r = c * a0r - s * a1r;
            float n0i = c * a0i - s * a1i;
            float n1r = s * a0r + c * a1r;
            float n1i = s * a0i + c * a1i;
            a0r = n0r; a0i = n0i; a1r = n1r; a1i = n1i;
        } else {
            int m = 1 << p;
            float sg = (lane & m) ? s : -s;
            float p0r = __shfl_xor(a0r, m, 64);
            float p0i = __shfl_xor(a0i, m, 64);
            float p1r = __shfl_xor(a1r, m, 64);
            float p1i = __shfl_xor(a1i, m, 64);
            a0r = fmaf(c, a0r, sg * p0r);
            a0i = fmaf(c, a0i, sg * p0i);
            a1r = fmaf(c, a1r, sg * p1r);
            a1i = fmaf(c, a1i, sg * p1i);
        }
    };

    auto mergedRZ = [&](int layer) {
        float base = 0.0f;
#pragma unroll
        for (int q = 1; q < NQ; ++q) {
            float h = 0.5f * wrz[layer * NQ + q];
            base += (lane & (1 << (6 - q))) ? -h : h;
        }
        float h0  = 0.5f * wrz[layer * NQ];
        float th0 = base + h0;
        float th1 = base - h0;
        float c0 = __cosf(th0), s0 = __sinf(th0);
        float c1 = __cosf(th1), s1 = __sinf(th1);
        float r, im;
        r = a0r; im = a0i;
        a0r = fmaf(c0, r, s0 * im);
        a0i = fmaf(c0, im, -s0 * r);
        r = a1r; im = a1i;
        a1r = fmaf(c1, r, s1 * im);
        a1i = fmaf(c1, im, -s1 * r);
    };

#pragma unroll
    for (int layer = 0; layer < NLAYERS; ++layer) {
        // combined RY block (layer 0's folded into init product)
        if (layer > 0) {
#pragma unroll
            for (int i = 0; i < NQ; ++i) {
                int t2 = (layer * NQ + i) * 2;
                float cw = trig[t2 + 0], sw = trig[t2 + 1];
                float c = dc[i] * cw - dsn[i] * sw;
                float s = dsn[i] * cw + dc[i] * sw;
                RY(c, s, i);
            }
        }

        mergedRZ(layer);

        // composed CNOT block: new[k] = old[g(k)], g linear over GF(2)
        {
            int s0 = 0;
#pragma unroll
            for (int j = 0; j < 6; ++j)
                s0 ^= (lane & (1 << j)) ? GCOL(layer, j) : 0;
            const int c6 = GCOL(layer, 6);
            int s1x = s0 ^ c6;
            int l0 = (s0 & 63) << 2, l1 = (s1x & 63) << 2;
            bool f0 = (s0 & 64) != 0;
            int aP0 = f0 ? l1 : l0;
            int aP1 = f0 ? l0 : l1;
            float g0, g1;
            g0 = bpermf(aP0, a0r); g1 = bpermf(aP1, a1r);
            a0r = f0 ? g1 : g0;  a1r = f0 ? g0 : g1;
            g0 = bpermf(aP0, a0i); g1 = bpermf(aP1, a1i);
            a0i = f0 ? g1 : g0;  a1i = f0 ? g0 : g1;
        }
    }

    float p0 = a0r * a0r + a0i * a0i;
    float p1 = a1r * a1r + a1i * a1i;
    float tp = p0 + p1;
    float tm = p0 - p1;

    // Walsh-Hadamard over the 6 lane bits
#pragma unroll
    for (int s = 0; s < 6; ++s) {
        int m = 1 << s;
        float pp = __shfl_xor(tp, m, 64);
        float pm = __shfl_xor(tm, m, 64);
        tp = (lane & m) ? (pp - tp) : (tp + pp);
        tm = (lane & m) ? (pm - tm) : (tm + pm);
    }

    float* qo = q_out + (size_t)wave * 14;
    int fp = -1;
    switch (lane) {
        case 32: fp = 1;  break;
        case 16: fp = 2;  break;
        case 8:  fp = 3;  break;
        case 4:  fp = 4;  break;
        case 2:  fp = 5;  break;
        case 1:  fp = 6;  break;
        case 48: fp = 8;  break;
        case 24: fp = 9;  break;
        case 12: fp = 10; break;
        case 6:  fp = 11; break;
        case 3:  fp = 12; break;
        default: break;
    }
    if (fp >= 0)    qo[fp] = tp;
    if (lane == 0)  qo[0]  = tm;
    if (lane == 32) qo[7]  = tm;
    if (lane == 1)  qo[13] = tm;
}

// ---------------------------------------------------------------------------
// One MFMA layer: Y[64][N] = act(X[64][K] @ Wt^T + b) into LDS (bf16).
// ---------------------------------------------------------------------------
template<int K, int NTILES, bool RELU>
__device__ __forceinline__ void layer_mfma(
    const unsigned short* src, unsigned short* dst,
    const unsigned short* __restrict__ wt, const float* __restrict__ bias,
    int dstcol, int lane, int wv)
{
    constexpr int KB   = K / 32;
    constexpr int NT_W = (NTILES > 4) ? NTILES / 4 : 1;
    constexpr int MT_W = NTILES / NT_W;
    const int ntile0 = (wv * NT_W) % NTILES;
    const int mtile0 = ((wv * NT_W) / NTILES) * MT_W;
    const int lcol = lane & 15;
    const int lrow = lane >> 4;

    bf16x8 bfrag[NT_W][KB];
    float  bb[NT_W];
#pragma unroll
    for (int n = 0; n < NT_W; ++n) {
#pragma unroll
        for (int kb = 0; kb < KB; ++kb)
            bfrag[n][kb] = *(const bf16x8*)&wt[((ntile0 + n) * 16 + lcol) * K + kb * 32 + lrow * 8];
        bb[n] = bias[(ntile0 + n) * 16 + lcol];
    }

#pragma unroll
    for (int m = 0; m < MT_W; ++m) {
        bf16x8 afrag[KB];
#pragma unroll
        for (int kb = 0; kb < KB; ++kb)
            afrag[kb] = *(const bf16x8*)&src[((mtile0 + m) * 16 + lcol) * LDS_S + kb * 32 + lrow * 8];

        f32x4 acc[NT_W];
#pragma unroll
        for (int n = 0; n < NT_W; ++n) acc[n] = (f32x4){bb[n], bb[n], bb[n], bb[n]};
#pragma unroll
        for (int kb = 0; kb < KB; ++kb)
#pragma unroll
            for (int n = 0; n < NT_W; ++n)
                acc[n] = __builtin_amdgcn_mfma_f32_16x16x32_bf16(afrag[kb], bfrag[n][kb], acc[n], 0, 0, 0);

#pragma unroll
        for (int n = 0; n < NT_W; ++n)
#pragma unroll
            for (int r = 0; r < 4; ++r) {
                float v = acc[n][r];
                if (RELU) v = fmaxf(v, 0.0f);
                dst[((mtile0 + m) * 16 + lrow * 4 + r) * LDS_S + dstcol + (ntile0 + n) * 16 + lcol] = f2bf(v);
            }
    }
}

// ---------------------------------------------------------------------------
// Fused MFMA MLP: 64 rows/block, 256 threads (4 waves).
// ---------------------------------------------------------------------------
__global__ __launch_bounds__(256, 4) void mlp_kernel(
    const float* __restrict__ q_out, const float* __restrict__ x_c,
    const unsigned short* __restrict__ ew1t, const float* __restrict__ eb1,
    const unsigned short* __restrict__ ew2t, const float* __restrict__ eb2,
    const unsigned short* __restrict__ w1t,  const float* __restrict__ b1,
    const unsigned short* __restrict__ w2t,  const float* __restrict__ b2,
    const unsigned short* __restrict__ w3t,  const float* __restrict__ b3,
    const unsigned short* __restrict__ w4t,  const float* __restrict__ b4,
    float* __restrict__ out, int B)
{
    __shared__ unsigned short BufA[ROWS * LDS_S];
    __shared__ unsigned short BufB[ROWS * LDS_S];

    const int tid  = threadIdx.x;
    const int lane = tid & 63;
    const int wv   = __builtin_amdgcn_readfirstlane(tid >> 6);
    const int base = blockIdx.x * ROWS;

    {
        const float4* xr = (const float4*)(x_c + (size_t)base * 64);
        for (int i = tid; i < 1024; i += 256) {
            int row = i >> 4, fc = i & 15;
            float4 v = xr[i];
            us4 b;
            b.x = f2bf(v.x); b.y = f2bf(v.y); b.z = f2bf(v.z); b.w = f2bf(v.w);
            *(us4*)&BufA[row * LDS_S + fc * 4] = b;
        }
    }
    for (int i = tid; i < 64 * 14; i += 256) {
        int row = i / 14, k = i - row * 14;
        BufA[row * LDS_S + 64 + k] = f2bf(q_out[(size_t)(base + row) * 14 + k]);
    }
    for (int i = tid; i < 64 * 18; i += 256) {
        int row = i / 18, k = i - row * 18;
        BufA[row * LDS_S + 110 + k] = 0;
    }
    __syncthreads();

    layer_mfma<64, 4, true>(BufA, BufB, ew1t, eb1, 0, lane, wv);
    __syncthreads();
    layer_mfma<64, 2, true>(BufB, BufA, ew2t, eb2, 78, lane, wv);
    __syncthreads();
    layer_mfma<128, 8, true>(BufA, BufB, w1t, b1, 0, lane, wv);
    __syncthreads();
    layer_mfma<128, 4, true>(BufB, BufA, w2t, b2, 0, lane, wv);
    __syncthreads();
    layer_mfma<64, 2, true>(BufA, BufB, w3t, b3, 0, lane, wv);
    __syncthreads();

    {
        const int lcol = lane & 15;
        const int lrow = lane >> 4;
        bf16x8 a = *(const bf16x8*)&BufB[(wv * 16 + lcol) * LDS_S + lrow * 8];
        bf16x8 b = *(const bf16x8*)&w4t[lcol * 32 + lrow * 8];
        float bv = b4[0];
        f32x4 acc = (f32x4){bv, bv, bv, bv};
        acc = __builtin_amdgcn_mfma_f32_16x16x32_bf16(a, b, acc, 0, 0, 0);
        if (lcol == 0) {
            float4 o; o.x = acc[0]; o.y = acc[1]; o.z = acc[2]; o.w = acc[3];
            *(float4*)(out + base + wv * 16 + lrow * 4) = o;
        }
    }
}

// ---------------------------------------------------------------------------
extern "C" void kernel_launch(void* const* d_in, const int* in_sizes, int n_in,
                              void* d_out, int out_size, void* d_ws, size_t ws_size,
                              hipStream_t stream)
{
    const float* x_q     = (const float*)d_in[0];
    const float* x_c     = (const float*)d_in[1];
    const float* scales  = (const float*)d_in[2];
    const float* biases  = (const float*)d_in[3];
    const float* wry     = (const float*)d_in[4];
    const float* wrz     = (const float*)d_in[5];
    const float* enc_w1  = (const float*)d_in[6];
    const float* enc_b1  = (const float*)d_in[7];
    const float* enc_w2  = (const float*)d_in[8];
    const float* enc_b2  = (const float*)d_in[9];
    const float* fus_w1  = (const float*)d_in[10];
    const float* fus_b1  = (const float*)d_in[11];
    const float* fus_w2  = (const float*)d_in[12];
    const float* fus_b2  = (const float*)d_in[13];
    const float* fus_w3  = (const float*)d_in[14];
    const float* fus_b3  = (const float*)d_in[15];
    const float* fus_w4  = (const float*)d_in[16];
    const float* fus_b4  = (const float*)d_in[17];
    float* out = (float*)d_out;

    int B = in_sizes[0] / NQ;   // 32768

    float* ws    = (float*)d_ws;
    float* q_out = ws;                              // B*14 floats
    float* trig  = ws + (size_t)B * 14;             // 48 floats (42 used)
    unsigned short* wsh = (unsigned short*)(trig + 48);
    unsigned short* w1t  = wsh;                     // 16384
    unsigned short* w2t  = w1t + 16384;             // 8192
    unsigned short* ew1t = w2t + 8192;              // 4096
    unsigned short* ew2t = ew1t + 4096;             // 2048
    unsigned short* w3t  = ew2t + 2048;             // 2048
    unsigned short* w4t  = w3t + 2048;              // 512

    precompute_kernel<<<1, 256, 0, stream>>>(wry, enc_w1, enc_w2,
                                             fus_w1, fus_w2, fus_w3, fus_w4,
                                             trig, ew1t, ew2t, w1t, w2t, w3t, w4t);

    int circ_blocks = (B * 64 + 255) / 256;
    circuit_kernel<<<circ_blocks, 256, 0, stream>>>(x_q, scales, biases, trig,
                                                    wrz, q_out, B);

    int row_blocks = B / ROWS;   // 512
    mlp_kernel<<<row_blocks, 256, 0, stream>>>(q_out, x_c,
                                               ew1t, enc_b1, ew2t, enc_b2,
                                               w1t, fus_b1, w2t, fus_b2,
                                               w3t, fus_b3, w4t, fus_b4,
                                               out, B);
}

// Round 6
// 57.618 us; speedup vs baseline: 5.3576x; 1.0724x over previous
//
#include <hip/hip_runtime.h>
#include <math.h>

#define NQ 7
#define DIM 128
#define NLAYERS 3
#define ROWS 64
#define LDS_S 136   // LDS row stride in bf16 units: 272 B = 17*16B (aligned b128, 2-way banks)

typedef __attribute__((ext_vector_type(8))) short bf16x8;
typedef __attribute__((ext_vector_type(4))) float f32x4;
typedef __attribute__((ext_vector_type(4))) unsigned short us4;

__device__ __forceinline__ unsigned short f2bf(float x) {
    union { float f; unsigned int u; } v; v.f = x;
    unsigned int r = v.u + 0x7fff + ((v.u >> 16) & 1);   // RNE
    return (unsigned short)(r >> 16);
}

// ===========================================================================
// Compile-time GF(2) linear algebra for CNOT-permutation deferral.
// Physical index p (7 bits): bit6 = register plane, bits5..0 = lane.
// λ maps physical -> logical state index; content(p) = v[λ(p)].
// ===========================================================================
constexpr int cperm(int k, int c, int t) {
    return k ^ (((k >> (6 - c)) & 1) << (6 - t));
}
constexpr int lgather(int k, int s) {
    int r = k;
    for (int i = 6; i >= 0; --i) r = cperm(r, i, (i + s) % 7);
    return r;
}

struct Mat { int c[7]; };   // c[j] = image of e_j (7-bit)

constexpr Mat ID{{1, 2, 4, 8, 16, 32, 64}};

constexpr int parity7(int x) { x ^= x >> 4; x ^= x >> 2; x ^= x >> 1; return x & 1; }

constexpr int mapv(const Mat& A, int v) {
    int r = 0;
    for (int j = 0; j < 7; ++j) if ((v >> j) & 1) r ^= A.c[j];
    return r;
}
constexpr Mat matmul(const Mat& A, const Mat& B) {   // A∘B
    Mat m{};
    for (int j = 0; j < 7; ++j) m.c[j] = mapv(A, B.c[j]);
    return m;
}
constexpr Mat matG(int L) {   // CNOT-block gather map g for layer L
    Mat m{};
    for (int j = 0; j < 7; ++j) m.c[j] = lgather(1 << j, L + 1);
    return m;
}
constexpr Mat matinv(const Mat& A) {
    int M[7] = {};
    for (int r = 0; r < 7; ++r) {
        int row = 0;
        for (int j = 0; j < 7; ++j) row |= ((A.c[j] >> r) & 1) << j;
        M[r] = row | (1 << (7 + r));
    }
    for (int col = 0; col < 7; ++col) {
        int piv = col;
        while (!((M[piv] >> col) & 1)) ++piv;
        int t = M[col]; M[col] = M[piv]; M[piv] = t;
        for (int r = 0; r < 7; ++r)
            if (r != col && ((M[r] >> col) & 1)) M[r] ^= M[col];
    }
    Mat inv{};
    for (int j = 0; j < 7; ++j) {
        int c = 0;
        for (int r = 0; r < 7; ++r) c |= ((M[r] >> (7 + j)) & 1) << r;
        inv.c[j] = c;
    }
    return inv;
}
constexpr bool isident(const Mat& A) {
    for (int j = 0; j < 7; ++j) if (A.c[j] != (1 << j)) return false;
    return true;
}

// λ after each CNOT block: λ' = g^{-1} ∘ λ
constexpr Mat LAM1  = matinv(matG(0));
constexpr Mat LAM2  = matmul(matinv(matG(1)), LAM1);
constexpr Mat LAM3  = matmul(matinv(matG(2)), LAM2);
constexpr Mat LAM1I = matG(0);
constexpr Mat LAM2I = matinv(LAM2);
static_assert(isident(matmul(LAM1, LAM1I)), "lam1 inv");
static_assert(isident(matmul(LAM2, LAM2I)), "lam2 inv");
static_assert(isident(matmul(matG(2), matmul(LAM3, matinv(LAM2)))), "lam3 chain");

// row b of λ as a bitmask over physical bits: <row,p> = bit b of λ(p)
constexpr int rowmask(const Mat& A, int b) {
    int r = 0;
    for (int j = 0; j < 7; ++j) r |= ((A.c[j] >> b) & 1) << j;
    return r;
}
// physical Walsh mask for logical mask m: M = λᵀ m
constexpr int featM(const Mat& A, int m) {
    int M = 0;
    for (int j = 0; j < 7; ++j) M |= parity7(A.c[j] & m) << j;
    return M;
}
constexpr int szzmask(int i) { return (1 << (6 - i)) | (1 << (6 - ((i + 1) % 7))); }

// ===========================================================================
// Cross-lane xor-exchange: DPP for masks {1,2,3,7,15}, ds shuffle otherwise.
// ===========================================================================
template<int M>
__device__ __forceinline__ float xsh(float v) {
    if constexpr (M == 1 || M == 2 || M == 3) {
        constexpr int ctrl = (0 ^ M) | ((1 ^ M) << 2) | ((2 ^ M) << 4) | ((3 ^ M) << 6);
        return __int_as_float(__builtin_amdgcn_update_dpp(
            __float_as_int(v), __float_as_int(v), ctrl, 0xF, 0xF, true));
    } else if constexpr (M == 7) {
        return __int_as_float(__builtin_amdgcn_update_dpp(
            __float_as_int(v), __float_as_int(v), 0x141, 0xF, 0xF, true));
    } else if constexpr (M == 15) {
        return __int_as_float(__builtin_amdgcn_update_dpp(
            __float_as_int(v), __float_as_int(v), 0x140, 0xF, 0xF, true));
    } else {
        return __shfl_xor(v, M, 64);
    }
}

// ===========================================================================
// Deferred-permutation RY gate on logical bit with partner mask D (physical)
// and sign row R: β(p) = parity(R & p). new = c*cur + (β ? +s : -s)*partner.
// ===========================================================================
template<int D, int R>
__device__ __forceinline__ void ryg(float c, float s, int lane,
                                    float& x0r, float& x0i, float& x1r, float& x1i)
{
    constexpr int  DL = D & 63;
    constexpr int  RL = R & 63;
    constexpr bool D6 = (D >> 6) & 1;
    constexpr bool R6 = (R >> 6) & 1;
    int par = __popc(lane & RL) & 1;
    float ns = -s;
    float sg0 = par ? s : ns;
    float sg1 = R6 ? (par ? ns : s) : sg0;
    float p0r, p0i, p1r, p1i;
    if constexpr (D6) {
        if constexpr (DL == 0) { p0r = x1r; p0i = x1i; p1r = x0r; p1i = x0i; }
        else {
            p0r = xsh<DL>(x1r); p0i = xsh<DL>(x1i);
            p1r = xsh<DL>(x0r); p1i = xsh<DL>(x0i);
        }
    } else {
        p0r = xsh<DL>(x0r); p0i = xsh<DL>(x0i);
        p1r = xsh<DL>(x1r); p1i = xsh<DL>(x1i);
    }
    x0r = fmaf(c, x0r, sg0 * p0r); x0i = fmaf(c, x0i, sg0 * p0i);
    x1r = fmaf(c, x1r, sg1 * p1r); x1i = fmaf(c, x1i, sg1 * p1i);
}

// combined data+weight RY gates of layer LYR (1 or 2), both elements
template<int LYR, int I>
__device__ __forceinline__ void rygates(
    const float* __restrict__ trig,
    const float (&dc)[2][NQ], const float (&dsn)[2][NQ], int lane,
    float (&A0r)[2], float (&A0i)[2], float (&A1r)[2], float (&A1i)[2])
{
    if constexpr (I < NQ) {
        constexpr Mat LM  = (LYR == 1) ? LAM1 : LAM2;
        constexpr Mat LMI = (LYR == 1) ? LAM1I : LAM2I;
        constexpr int b   = 6 - I;
        constexpr int D   = mapv(LMI, 1 << b);
        constexpr int R   = rowmask(LM, b);
        float cw = trig[(LYR * NQ + I) * 2 + 0];
        float sw = trig[(LYR * NQ + I) * 2 + 1];
#pragma unroll
        for (int e = 0; e < 2; ++e) {
            float c = dc[e][I] * cw - dsn[e][I] * sw;   // RY(a)RY(b)=RY(a+b)
            float s = dsn[e][I] * cw + dc[e][I] * sw;
            ryg<D, R>(c, s, lane, A0r[e], A0i[e], A1r[e], A1i[e]);
        }
        rygates<LYR, I + 1>(trig, dc, dsn, lane, A0r, A0i, A1r, A1i);
    }
}

// merged-RZ sign accumulation rows (deferred space)
template<int LYR, int Q>
__device__ __forceinline__ void rzrows(const float* __restrict__ wrz, int lane,
                                       float& Aacc, float& Bacc)
{
    if constexpr (Q < NQ) {
        constexpr Mat LM = (LYR == 0) ? ID : ((LYR == 1) ? LAM1 : LAM2);
        constexpr int R  = rowmask(LM, 6 - Q);
        float h = 0.5f * wrz[LYR * NQ + Q];
        float t = (__popc(lane & (R & 63)) & 1) ? -h : h;
        if constexpr ((R >> 6) & 1) Bacc += t; else Aacc += t;
        rzrows<LYR, Q + 1>(wrz, lane, Aacc, Bacc);
    }
}

template<int LYR>
__device__ __forceinline__ void rzlayer(const float* __restrict__ wrz, int lane,
    float (&A0r)[2], float (&A0i)[2], float (&A1r)[2], float (&A1i)[2])
{
    float Aacc = 0.0f, Bacc = 0.0f;
    rzrows<LYR, 0>(wrz, lane, Aacc, Bacc);
    float th0 = Aacc + Bacc, th1 = Aacc - Bacc;
    float c0 = __cosf(th0), s0 = __sinf(th0);
    float c1 = __cosf(th1), s1 = __sinf(th1);
#pragma unroll
    for (int e = 0; e < 2; ++e) {
        float r = A0r[e], im = A0i[e];
        A0r[e] = fmaf(c0, r, s0 * im);        // * exp(-i*th0)
        A0i[e] = fmaf(c0, im, -s0 * r);
        r = A1r[e]; im = A1i[e];
        A1r[e] = fmaf(c1, r, s1 * im);
        A1i[e] = fmaf(c1, im, -s1 * r);
    }
}

// Walsh-Hadamard butterfly stage over lane-bit mask M
template<int M>
__device__ __forceinline__ void bfly(int lane, float& tp, float& tm) {
    float pp = xsh<M>(tp), pm = xsh<M>(tm);
    bool hi = (lane & M) != 0;
    tp = hi ? (pp - tp) : (tp + pp);
    tm = hi ? (pm - tm) : (tm + pm);
}

// feature extraction at compile-time-transformed Walsh masks
template<int F>
__device__ __forceinline__ void feats(int lane, float tp, float tm,
                                      float* __restrict__ qo) {
    if constexpr (F < 14) {
        constexpr int m = (F < 7) ? (64 >> F) : szzmask(F - 7);
        constexpr int M = featM(LAM3, m);
        if (lane == (M & 63)) qo[F] = ((M >> 6) & 1) ? tm : tp;
        feats<F + 1>(lane, tp, tm, qo);
    }
}

// ---------------------------------------------------------------------------
// Precompute: circuit trig + all MLP weights transposed to [N][Kp] bf16.
// ---------------------------------------------------------------------------
__global__ __launch_bounds__(256) void precompute_kernel(
    const float* __restrict__ wry,
    const float* __restrict__ ew1, const float* __restrict__ ew2,
    const float* __restrict__ w1,  const float* __restrict__ w2,
    const float* __restrict__ w3,  const float* __restrict__ w4,
    float* __restrict__ trig,
    unsigned short* __restrict__ ew1t, unsigned short* __restrict__ ew2t,
    unsigned short* __restrict__ w1t,  unsigned short* __restrict__ w2t,
    unsigned short* __restrict__ w3t,  unsigned short* __restrict__ w4t)
{
    int tid = threadIdx.x;
    if (tid < NLAYERS * NQ) {
        float hy = 0.5f * wry[tid];
        trig[tid * 2 + 0] = cosf(hy);
        trig[tid * 2 + 1] = sinf(hy);
    }
    for (int i = tid; i < 4096; i += 256) {
        int n = i >> 6, k = i & 63;
        ew1t[i] = f2bf(ew1[k * 64 + n]);
    }
    for (int i = tid; i < 2048; i += 256) {
        int n = i >> 6, k = i & 63;
        ew2t[i] = f2bf(ew2[k * 32 + n]);
    }
    for (int i = tid; i < 16384; i += 256) {
        int n = i >> 7, kp = i & 127;
        unsigned short v = 0;
        if (kp < 64)        v = f2bf(w1[(46 + kp) * 128 + n]);
        else if (kp < 78)   v = f2bf(w1[(kp - 64) * 128 + n]);
        else if (kp < 110)  v = f2bf(w1[(kp - 78 + 14) * 128 + n]);
        w1t[i] = v;
    }
    for (int i = tid; i < 8192; i += 256) {
        int n = i >> 7, k = i & 127;
        w2t[i] = f2bf(w2[k * 64 + n]);
    }
    for (int i = tid; i < 2048; i += 256) {
        int n = i >> 6, k = i & 63;
        w3t[i] = f2bf(w3[k * 32 + n]);
    }
    for (int i = tid; i < 512; i += 256) {
        int n = i >> 5, k = i & 31;
        w4t[i] = (n == 0) ? f2bf(w4[k]) : (unsigned short)0;
    }
}

// ---------------------------------------------------------------------------
// Quantum circuit: one wave handles TWO batch elements (2 independent chains).
// CNOT blocks fully deferred via compile-time linear remap; features read in
// permuted Walsh space.
// ---------------------------------------------------------------------------
__global__ __launch_bounds__(256) void circuit_kernel(
    const float* __restrict__ x_q, const float* __restrict__ scales,
    const float* __restrict__ biases, const float* __restrict__ trig,
    const float* __restrict__ wrz,
    float* __restrict__ q_out, int B)
{
    int gtid = blockIdx.x * blockDim.x + threadIdx.x;
    int wv   = gtid >> 6;
    int lane = threadIdx.x & 63;
    int e0   = wv * 2;
    if (e0 >= B) return;

    // data half-angle trig (hw sin/cos), both elements
    float dc[2][NQ], dsn[2][NQ];
#pragma unroll
    for (int e = 0; e < 2; ++e)
#pragma unroll
        for (int i = 0; i < NQ; ++i) {
            float h = 0.5f * fmaf(scales[i], x_q[(e0 + e) * NQ + i], biases[i]);
            dc[e][i]  = __cosf(h);
            dsn[e][i] = __sinf(h);
        }

    // layer-0 combined (data+weight) RY block on |0...0>: product state (λ=id)
    float A0r[2], A0i[2], A1r[2], A1i[2];
#pragma unroll
    for (int e = 0; e < 2; ++e) {
        float cl[NQ], sl[NQ];
#pragma unroll
        for (int i = 0; i < NQ; ++i) {
            float cw = trig[i * 2 + 0], sw = trig[i * 2 + 1];
            cl[i] = dc[e][i] * cw - dsn[e][i] * sw;
            sl[i] = dsn[e][i] * cw + dc[e][i] * sw;
        }
        float f1 = (lane & 32) ? sl[1] : cl[1];
        float f2 = (lane & 16) ? sl[2] : cl[2];
        float f3 = (lane &  8) ? sl[3] : cl[3];
        float f4 = (lane &  4) ? sl[4] : cl[4];
        float f5 = (lane &  2) ? sl[5] : cl[5];
        float f6 = (lane &  1) ? sl[6] : cl[6];
        float pr = (f1 * f2) * (f3 * f4) * (f5 * f6);
        A0r[e] = pr * cl[0]; A0i[e] = 0.0f;
        A1r[e] = pr * sl[0]; A1i[e] = 0.0f;
    }

    rzlayer<0>(wrz, lane, A0r, A0i, A1r, A1i);
    // CNOT block 1 deferred (λ -> LAM1)
    rygates<1, 0>(trig, dc, dsn, lane, A0r, A0i, A1r, A1i);
    rzlayer<1>(wrz, lane, A0r, A0i, A1r, A1i);
    // CNOT block 2 deferred (λ -> LAM2)
    rygates<2, 0>(trig, dc, dsn, lane, A0r, A0i, A1r, A1i);
    rzlayer<2>(wrz, lane, A0r, A0i, A1r, A1i);
    // CNOT block 3 deferred (λ -> LAM3, folded into feature masks)

#pragma unroll
    for (int e = 0; e < 2; ++e) {
        float p0 = A0r[e] * A0r[e] + A0i[e] * A0i[e];
        float p1 = A1r[e] * A1r[e] + A1i[e] * A1i[e];
        float tp = p0 + p1;   // physical-Walsh masks with bit6 = 0
        float tm = p0 - p1;   // physical-Walsh masks with bit6 = 1

        bfly<1>(lane, tp, tm);
        bfly<2>(lane, tp, tm);
        bfly<4>(lane, tp, tm);
        bfly<8>(lane, tp, tm);
        bfly<16>(lane, tp, tm);
        bfly<32>(lane, tp, tm);

        feats<0>(lane, tp, tm, q_out + (size_t)(e0 + e) * 14);
    }
}

// ---------------------------------------------------------------------------
// One MFMA layer: Y[64][N] = act(X[64][K] @ Wt^T + b) into LDS (bf16).
// ---------------------------------------------------------------------------
template<int K, int NTILES, bool RELU>
__device__ __forceinline__ void layer_mfma(
    const unsigned short* src, unsigned short* dst,
    const unsigned short* __restrict__ wt, const float* __restrict__ bias,
    int dstcol, int lane, int wv)
{
    constexpr int KB   = K / 32;
    constexpr int NT_W = (NTILES > 4) ? NTILES / 4 : 1;
    constexpr int MT_W = NTILES / NT_W;
    const int ntile0 = (wv * NT_W) % NTILES;
    const int mtile0 = ((wv * NT_W) / NTILES) * MT_W;
    const int lcol = lane & 15;
    const int lrow = lane >> 4;

    bf16x8 bfrag[NT_W][KB];
    float  bb[NT_W];
#pragma unroll
    for (int n = 0; n < NT_W; ++n) {
#pragma unroll
        for (int kb = 0; kb < KB; ++kb)
            bfrag[n][kb] = *(const bf16x8*)&wt[((ntile0 + n) * 16 + lcol) * K + kb * 32 + lrow * 8];
        bb[n] = bias[(ntile0 + n) * 16 + lcol];
    }

#pragma unroll
    for (int m = 0; m < MT_W; ++m) {
        bf16x8 afrag[KB];
#pragma unroll
        for (int kb = 0; kb < KB; ++kb)
            afrag[kb] = *(const bf16x8*)&src[((mtile0 + m) * 16 + lcol) * LDS_S + kb * 32 + lrow * 8];

        f32x4 acc[NT_W];
#pragma unroll
        for (int n = 0; n < NT_W; ++n) acc[n] = (f32x4){bb[n], bb[n], bb[n], bb[n]};
#pragma unroll
        for (int kb = 0; kb < KB; ++kb)
#pragma unroll
            for (int n = 0; n < NT_W; ++n)
                acc[n] = __builtin_amdgcn_mfma_f32_16x16x32_bf16(afrag[kb], bfrag[n][kb], acc[n], 0, 0, 0);

#pragma unroll
        for (int n = 0; n < NT_W; ++n)
#pragma unroll
            for (int r = 0; r < 4; ++r) {
                float v = acc[n][r];
                if (RELU) v = fmaxf(v, 0.0f);
                dst[((mtile0 + m) * 16 + lrow * 4 + r) * LDS_S + dstcol + (ntile0 + n) * 16 + lcol] = f2bf(v);
            }
    }
}

// ---------------------------------------------------------------------------
// Fused MFMA MLP: 64 rows/block, 256 threads (4 waves).
// ---------------------------------------------------------------------------
__global__ __launch_bounds__(256, 4) void mlp_kernel(
    const float* __restrict__ q_out, const float* __restrict__ x_c,
    const unsigned short* __restrict__ ew1t, const float* __restrict__ eb1,
    const unsigned short* __restrict__ ew2t, const float* __restrict__ eb2,
    const unsigned short* __restrict__ w1t,  const float* __restrict__ b1,
    const unsigned short* __restrict__ w2t,  const float* __restrict__ b2,
    const unsigned short* __restrict__ w3t,  const float* __restrict__ b3,
    const unsigned short* __restrict__ w4t,  const float* __restrict__ b4,
    float* __restrict__ out, int B)
{
    __shared__ unsigned short BufA[ROWS * LDS_S];
    __shared__ unsigned short BufB[ROWS * LDS_S];

    const int tid  = threadIdx.x;
    const int lane = tid & 63;
    const int wv   = __builtin_amdgcn_readfirstlane(tid >> 6);
    const int base = blockIdx.x * ROWS;

    {
        const float4* xr = (const float4*)(x_c + (size_t)base * 64);
        for (int i = tid; i < 1024; i += 256) {
            int row = i >> 4, fc = i & 15;
            float4 v = xr[i];
            us4 b;
            b.x = f2bf(v.x); b.y = f2bf(v.y); b.z = f2bf(v.z); b.w = f2bf(v.w);
            *(us4*)&BufA[row * LDS_S + fc * 4] = b;
        }
    }
    for (int i = tid; i < 64 * 14; i += 256) {
        int row = i / 14, k = i - row * 14;
        BufA[row * LDS_S + 64 + k] = f2bf(q_out[(size_t)(base + row) * 14 + k]);
    }
    for (int i = tid; i < 64 * 18; i += 256) {
        int row = i / 18, k = i - row * 18;
        BufA[row * LDS_S + 110 + k] = 0;
    }
    __syncthreads();

    layer_mfma<64, 4, true>(BufA, BufB, ew1t, eb1, 0, lane, wv);
    __syncthreads();
    layer_mfma<64, 2, true>(BufB, BufA, ew2t, eb2, 78, lane, wv);
    __syncthreads();
    layer_mfma<128, 8, true>(BufA, BufB, w1t, b1, 0, lane, wv);
    __syncthreads();
    layer_mfma<128, 4, true>(BufB, BufA, w2t, b2, 0, lane, wv);
    __syncthreads();
    layer_mfma<64, 2, true>(BufA, BufB, w3t, b3, 0, lane, wv);
    __syncthreads();

    {
        const int lcol = lane & 15;
        const int lrow = lane >> 4;
        bf16x8 a = *(const bf16x8*)&BufB[(wv * 16 + lcol) * LDS_S + lrow * 8];
        bf16x8 b = *(const bf16x8*)&w4t[lcol * 32 + lrow * 8];
        float bv = b4[0];
        f32x4 acc = (f32x4){bv, bv, bv, bv};
        acc = __builtin_amdgcn_mfma_f32_16x16x32_bf16(a, b, acc, 0, 0, 0);
        if (lcol == 0) {
            float4 o; o.x = acc[0]; o.y = acc[1]; o.z = acc[2]; o.w = acc[3];
            *(float4*)(out + base + wv * 16 + lrow * 4) = o;
        }
    }
}

// ---------------------------------------------------------------------------
extern "C" void kernel_launch(void* const* d_in, const int* in_sizes, int n_in,
                              void* d_out, int out_size, void* d_ws, size_t ws_size,
                              hipStream_t stream)
{
    const float* x_q     = (const float*)d_in[0];
    const float* x_c     = (const float*)d_in[1];
    const float* scales  = (const float*)d_in[2];
    const float* biases  = (const float*)d_in[3];
    const float* wry     = (const float*)d_in[4];
    const float* wrz     = (const float*)d_in[5];
    const float* enc_w1  = (const float*)d_in[6];
    const float* enc_b1  = (const float*)d_in[7];
    const float* enc_w2  = (const float*)d_in[8];
    const float* enc_b2  = (const float*)d_in[9];
    const float* fus_w1  = (const float*)d_in[10];
    const float* fus_b1  = (const float*)d_in[11];
    const float* fus_w2  = (const float*)d_in[12];
    const float* fus_b2  = (const float*)d_in[13];
    const float* fus_w3  = (const float*)d_in[14];
    const float* fus_b3  = (const float*)d_in[15];
    const float* fus_w4  = (const float*)d_in[16];
    const float* fus_b4  = (const float*)d_in[17];
    float* out = (float*)d_out;

    int B = in_sizes[0] / NQ;   // 32768

    float* ws    = (float*)d_ws;
    float* q_out = ws;                              // B*14 floats
    float* trig  = ws + (size_t)B * 14;             // 48 floats (42 used)
    unsigned short* wsh = (unsigned short*)(trig + 48);
    unsigned short* w1t  = wsh;                     // 16384
    unsigned short* w2t  = w1t + 16384;             // 8192
    unsigned short* ew1t = w2t + 8192;              // 4096
    unsigned short* ew2t = ew1t + 4096;             // 2048
    unsigned short* w3t  = ew2t + 2048;             // 2048
    unsigned short* w4t  = w3t + 2048;              // 512

    precompute_kernel<<<1, 256, 0, stream>>>(wry, enc_w1, enc_w2,
                                             fus_w1, fus_w2, fus_w3, fus_w4,
                                             trig, ew1t, ew2t, w1t, w2t, w3t, w4t);

    int circ_blocks = ((B / 2) * 64 + 255) / 256;   // 2 elements per wave
    circuit_kernel<<<circ_blocks, 256, 0, stream>>>(x_q, scales, biases, trig,
                                                    wrz, q_out, B);

    int row_blocks = B / ROWS;   // 512
    mlp_kernel<<<row_blocks, 256, 0, stream>>>(q_out, x_c,
                                               ew1t, enc_b1, ew2t, enc_b2,
                                               w1t, fus_b1, w2t, fus_b2,
                                               w3t, fus_b3, w4t, fus_b4,
                                               out, B);
}

// Round 7
// 38.641 us; speedup vs baseline: 7.9887x; 1.4911x over previous
//
#include <hip/hip_runtime.h>
#include <math.h>

#define NQ 7
#define DIM 128
#define NLAYERS 3
#define ROWS 64
#define LDS_S 136   // LDS row stride in bf16 units: 272 B = 17*16B (aligned b128, 2-way banks)

typedef __attribute__((ext_vector_type(8))) short bf16x8;
typedef __attribute__((ext_vector_type(4))) float f32x4;
typedef __attribute__((ext_vector_type(4))) unsigned short us4;

__device__ __forceinline__ unsigned short f2bf(float x) {
    union { float f; unsigned int u; } v; v.f = x;
    unsigned int r = v.u + 0x7fff + ((v.u >> 16) & 1);   // RNE
    return (unsigned short)(r >> 16);
}

// ===========================================================================
// Compile-time GF(2) linear algebra for CNOT-permutation deferral.
// Physical index p (7 bits): bit6 = register plane, bits5..0 = lane.
// λ maps physical -> logical state index; content(p) = v[λ(p)].
// ===========================================================================
constexpr int cperm(int k, int c, int t) {
    return k ^ (((k >> (6 - c)) & 1) << (6 - t));
}
constexpr int lgather(int k, int s) {
    int r = k;
    for (int i = 6; i >= 0; --i) r = cperm(r, i, (i + s) % 7);
    return r;
}

struct Mat { int c[7]; };   // c[j] = image of e_j (7-bit)

constexpr Mat ID{{1, 2, 4, 8, 16, 32, 64}};

constexpr int parity7(int x) { x ^= x >> 4; x ^= x >> 2; x ^= x >> 1; return x & 1; }

constexpr int mapv(const Mat& A, int v) {
    int r = 0;
    for (int j = 0; j < 7; ++j) if ((v >> j) & 1) r ^= A.c[j];
    return r;
}
constexpr Mat matmul(const Mat& A, const Mat& B) {   // A∘B
    Mat m{};
    for (int j = 0; j < 7; ++j) m.c[j] = mapv(A, B.c[j]);
    return m;
}
constexpr Mat matG(int L) {   // CNOT-block gather map g for layer L
    Mat m{};
    for (int j = 0; j < 7; ++j) m.c[j] = lgather(1 << j, L + 1);
    return m;
}
constexpr Mat matinv(const Mat& A) {
    int M[7] = {};
    for (int r = 0; r < 7; ++r) {
        int row = 0;
        for (int j = 0; j < 7; ++j) row |= ((A.c[j] >> r) & 1) << j;
        M[r] = row | (1 << (7 + r));
    }
    for (int col = 0; col < 7; ++col) {
        int piv = col;
        while (!((M[piv] >> col) & 1)) ++piv;
        int t = M[col]; M[col] = M[piv]; M[piv] = t;
        for (int r = 0; r < 7; ++r)
            if (r != col && ((M[r] >> col) & 1)) M[r] ^= M[col];
    }
    Mat inv{};
    for (int j = 0; j < 7; ++j) {
        int c = 0;
        for (int r = 0; r < 7; ++r) c |= ((M[r] >> (7 + j)) & 1) << r;
        inv.c[j] = c;
    }
    return inv;
}
constexpr bool isident(const Mat& A) {
    for (int j = 0; j < 7; ++j) if (A.c[j] != (1 << j)) return false;
    return true;
}

// λ after each CNOT block: λ' = g^{-1} ∘ λ
constexpr Mat LAM1  = matinv(matG(0));
constexpr Mat LAM2  = matmul(matinv(matG(1)), LAM1);
constexpr Mat LAM3  = matmul(matinv(matG(2)), LAM2);
constexpr Mat LAM1I = matG(0);
constexpr Mat LAM2I = matinv(LAM2);
static_assert(isident(matmul(LAM1, LAM1I)), "lam1 inv");
static_assert(isident(matmul(LAM2, LAM2I)), "lam2 inv");
static_assert(isident(matmul(matG(2), matmul(LAM3, matinv(LAM2)))), "lam3 chain");

// row b of λ as a bitmask over physical bits: <row,p> = bit b of λ(p)
constexpr int rowmask(const Mat& A, int b) {
    int r = 0;
    for (int j = 0; j < 7; ++j) r |= ((A.c[j] >> b) & 1) << j;
    return r;
}
// physical Walsh mask for logical mask m: M = λᵀ m
constexpr int featM(const Mat& A, int m) {
    int M = 0;
    for (int j = 0; j < 7; ++j) M |= parity7(A.c[j] & m) << j;
    return M;
}
constexpr int szzmask(int i) { return (1 << (6 - i)) | (1 << (6 - ((i + 1) % 7))); }

// ===========================================================================
// Cross-lane xor-exchange: DPP for masks {1,2,3,7,15}, ds shuffle otherwise.
// ===========================================================================
template<int M>
__device__ __forceinline__ float xsh(float v) {
    if constexpr (M == 1 || M == 2 || M == 3) {
        constexpr int ctrl = (0 ^ M) | ((1 ^ M) << 2) | ((2 ^ M) << 4) | ((3 ^ M) << 6);
        return __int_as_float(__builtin_amdgcn_update_dpp(
            __float_as_int(v), __float_as_int(v), ctrl, 0xF, 0xF, true));
    } else if constexpr (M == 7) {
        return __int_as_float(__builtin_amdgcn_update_dpp(
            __float_as_int(v), __float_as_int(v), 0x141, 0xF, 0xF, true));
    } else if constexpr (M == 15) {
        return __int_as_float(__builtin_amdgcn_update_dpp(
            __float_as_int(v), __float_as_int(v), 0x140, 0xF, 0xF, true));
    } else {
        return __shfl_xor(v, M, 64);
    }
}

// ===========================================================================
// Deferred-permutation RY gate on logical bit with partner mask D (physical)
// and sign row R: β(p) = parity(R & p). new = c*cur + (β ? +s : -s)*partner.
// ===========================================================================
template<int D, int R>
__device__ __forceinline__ void ryg(float c, float s, int lane,
                                    float& x0r, float& x0i, float& x1r, float& x1i)
{
    constexpr int  DL = D & 63;
    constexpr int  RL = R & 63;
    constexpr bool D6 = (D >> 6) & 1;
    constexpr bool R6 = (R >> 6) & 1;
    int par = __popc(lane & RL) & 1;
    float ns = -s;
    float sg0 = par ? s : ns;
    float sg1 = R6 ? (par ? ns : s) : sg0;
    float p0r, p0i, p1r, p1i;
    if constexpr (D6) {
        if constexpr (DL == 0) { p0r = x1r; p0i = x1i; p1r = x0r; p1i = x0i; }
        else {
            p0r = xsh<DL>(x1r); p0i = xsh<DL>(x1i);
            p1r = xsh<DL>(x0r); p1i = xsh<DL>(x0i);
        }
    } else {
        p0r = xsh<DL>(x0r); p0i = xsh<DL>(x0i);
        p1r = xsh<DL>(x1r); p1i = xsh<DL>(x1i);
    }
    x0r = fmaf(c, x0r, sg0 * p0r); x0i = fmaf(c, x0i, sg0 * p0i);
    x1r = fmaf(c, x1r, sg1 * p1r); x1i = fmaf(c, x1i, sg1 * p1i);
}

// combined data+weight RY gates of layer LYR (1 or 2), both elements
template<int LYR, int I>
__device__ __forceinline__ void rygates(
    const float* trig,
    const float (&dc)[2][NQ], const float (&dsn)[2][NQ], int lane,
    float (&A0r)[2], float (&A0i)[2], float (&A1r)[2], float (&A1i)[2])
{
    if constexpr (I < NQ) {
        constexpr Mat LM  = (LYR == 1) ? LAM1 : LAM2;
        constexpr Mat LMI = (LYR == 1) ? LAM1I : LAM2I;
        constexpr int b   = 6 - I;
        constexpr int D   = mapv(LMI, 1 << b);
        constexpr int R   = rowmask(LM, b);
        float cw = trig[(LYR * NQ + I) * 2 + 0];
        float sw = trig[(LYR * NQ + I) * 2 + 1];
#pragma unroll
        for (int e = 0; e < 2; ++e) {
            float c = dc[e][I] * cw - dsn[e][I] * sw;   // RY(a)RY(b)=RY(a+b)
            float s = dsn[e][I] * cw + dc[e][I] * sw;
            ryg<D, R>(c, s, lane, A0r[e], A0i[e], A1r[e], A1i[e]);
        }
        rygates<LYR, I + 1>(trig, dc, dsn, lane, A0r, A0i, A1r, A1i);
    }
}

// merged-RZ sign accumulation rows (deferred space)
template<int LYR, int Q>
__device__ __forceinline__ void rzrows(const float* __restrict__ wrz, int lane,
                                       float& Aacc, float& Bacc)
{
    if constexpr (Q < NQ) {
        constexpr Mat LM = (LYR == 0) ? ID : ((LYR == 1) ? LAM1 : LAM2);
        constexpr int R  = rowmask(LM, 6 - Q);
        float h = 0.5f * wrz[LYR * NQ + Q];
        float t = (__popc(lane & (R & 63)) & 1) ? -h : h;
        if constexpr ((R >> 6) & 1) Bacc += t; else Aacc += t;
        rzrows<LYR, Q + 1>(wrz, lane, Aacc, Bacc);
    }
}

template<int LYR>
__device__ __forceinline__ void rzlayer(const float* __restrict__ wrz, int lane,
    float (&A0r)[2], float (&A0i)[2], float (&A1r)[2], float (&A1i)[2])
{
    float Aacc = 0.0f, Bacc = 0.0f;
    rzrows<LYR, 0>(wrz, lane, Aacc, Bacc);
    float th0 = Aacc + Bacc, th1 = Aacc - Bacc;
    float c0 = __cosf(th0), s0 = __sinf(th0);
    float c1 = __cosf(th1), s1 = __sinf(th1);
#pragma unroll
    for (int e = 0; e < 2; ++e) {
        float r = A0r[e], im = A0i[e];
        A0r[e] = fmaf(c0, r, s0 * im);        // * exp(-i*th0)
        A0i[e] = fmaf(c0, im, -s0 * r);
        r = A1r[e]; im = A1i[e];
        A1r[e] = fmaf(c1, r, s1 * im);
        A1i[e] = fmaf(c1, im, -s1 * r);
    }
}

// Walsh-Hadamard butterfly stage over lane-bit mask M
template<int M>
__device__ __forceinline__ void bfly(int lane, float& tp, float& tm) {
    float pp = xsh<M>(tp), pm = xsh<M>(tm);
    bool hi = (lane & M) != 0;
    tp = hi ? (pp - tp) : (tp + pp);
    tm = hi ? (pm - tm) : (tm + pm);
}

// feature extraction at compile-time-transformed Walsh masks
template<int F>
__device__ __forceinline__ void feats(int lane, float tp, float tm,
                                      float* __restrict__ qo) {
    if constexpr (F < 14) {
        constexpr int m = (F < 7) ? (64 >> F) : szzmask(F - 7);
        constexpr int M = featM(LAM3, m);
        if (lane == (M & 63)) qo[F] = ((M >> 6) & 1) ? tm : tp;
        feats<F + 1>(lane, tp, tm, qo);
    }
}

// ---------------------------------------------------------------------------
// Quantum circuit (one wave = 2 batch elements) + folded-in precompute:
//  - weight-angle trig computed per-block into LDS (21 hw sincos, shared)
//  - blocks 0..63 additionally transpose all MLP weights to [N][Kp] bf16
//    (runs in parallel with other blocks' circuit work; mlp kernel waits on
//     kernel completion, so ordering is guaranteed)
// ---------------------------------------------------------------------------
__global__ __launch_bounds__(256) void circuit_kernel(
    const float* __restrict__ x_q, const float* __restrict__ scales,
    const float* __restrict__ biases,
    const float* __restrict__ wry, const float* __restrict__ wrz,
    const float* __restrict__ ew1, const float* __restrict__ ew2,
    const float* __restrict__ w1,  const float* __restrict__ w2,
    const float* __restrict__ w3,  const float* __restrict__ w4,
    float* __restrict__ q_out,
    unsigned short* __restrict__ ew1t, unsigned short* __restrict__ ew2t,
    unsigned short* __restrict__ w1t,  unsigned short* __restrict__ w2t,
    unsigned short* __restrict__ w3t,  unsigned short* __restrict__ w4t,
    int B)
{
    __shared__ float strig[NLAYERS * NQ * 2];
    const int tid  = threadIdx.x;
    const int lane = tid & 63;

    if (tid < NLAYERS * NQ) {
        float hy = 0.5f * wry[tid];
        strig[tid * 2 + 0] = __cosf(hy);
        strig[tid * 2 + 1] = __sinf(hy);
    }

    // ---- weight transposition, spread over blocks 0..63 (parallel prologue)
    if (blockIdx.x < 64) {
        const int gbase  = blockIdx.x * 256 + tid;
        const int stride = 64 * 256;
        for (int i = gbase; i < 16384; i += stride) {          // w1t (permuted K)
            int n = i >> 7, kp = i & 127;
            unsigned short v = 0;
            if (kp < 64)        v = f2bf(w1[(46 + kp) * 128 + n]);
            else if (kp < 78)   v = f2bf(w1[(kp - 64) * 128 + n]);
            else if (kp < 110)  v = f2bf(w1[(kp - 78 + 14) * 128 + n]);
            w1t[i] = v;
        }
        for (int i = gbase; i < 8192; i += stride) {           // w2t
            int n = i >> 7, k = i & 127;
            w2t[i] = f2bf(w2[k * 64 + n]);
        }
        for (int i = gbase; i < 4096; i += stride) {           // ew1t
            int n = i >> 6, k = i & 63;
            ew1t[i] = f2bf(ew1[k * 64 + n]);
        }
        for (int i = gbase; i < 2048; i += stride) {           // ew2t
            int n = i >> 6, k = i & 63;
            ew2t[i] = f2bf(ew2[k * 32 + n]);
        }
        for (int i = gbase; i < 2048; i += stride) {           // w3t
            int n = i >> 6, k = i & 63;
            w3t[i] = f2bf(w3[k * 32 + n]);
        }
        for (int i = gbase; i < 512; i += stride) {            // w4t
            int n = i >> 5, k = i & 31;
            w4t[i] = (n == 0) ? f2bf(w4[k]) : (unsigned short)0;
        }
    }
    __syncthreads();

    int gtid = blockIdx.x * blockDim.x + tid;
    int wv   = gtid >> 6;
    int e0   = wv * 2;
    if (e0 >= B) return;

    // data half-angle trig (hw sin/cos), both elements
    float dc[2][NQ], dsn[2][NQ];
#pragma unroll
    for (int e = 0; e < 2; ++e)
#pragma unroll
        for (int i = 0; i < NQ; ++i) {
            float h = 0.5f * fmaf(scales[i], x_q[(e0 + e) * NQ + i], biases[i]);
            dc[e][i]  = __cosf(h);
            dsn[e][i] = __sinf(h);
        }

    // layer-0 combined (data+weight) RY block on |0...0>: product state (λ=id)
    float A0r[2], A0i[2], A1r[2], A1i[2];
#pragma unroll
    for (int e = 0; e < 2; ++e) {
        float cl[NQ], sl[NQ];
#pragma unroll
        for (int i = 0; i < NQ; ++i) {
            float cw = strig[i * 2 + 0], sw = strig[i * 2 + 1];
            cl[i] = dc[e][i] * cw - dsn[e][i] * sw;
            sl[i] = dsn[e][i] * cw + dc[e][i] * sw;
        }
        float f1 = (lane & 32) ? sl[1] : cl[1];
        float f2 = (lane & 16) ? sl[2] : cl[2];
        float f3 = (lane &  8) ? sl[3] : cl[3];
        float f4 = (lane &  4) ? sl[4] : cl[4];
        float f5 = (lane &  2) ? sl[5] : cl[5];
        float f6 = (lane &  1) ? sl[6] : cl[6];
        float pr = (f1 * f2) * (f3 * f4) * (f5 * f6);
        A0r[e] = pr * cl[0]; A0i[e] = 0.0f;
        A1r[e] = pr * sl[0]; A1i[e] = 0.0f;
    }

    rzlayer<0>(wrz, lane, A0r, A0i, A1r, A1i);
    // CNOT block 1 deferred (λ -> LAM1)
    rygates<1, 0>(strig, dc, dsn, lane, A0r, A0i, A1r, A1i);
    rzlayer<1>(wrz, lane, A0r, A0i, A1r, A1i);
    // CNOT block 2 deferred (λ -> LAM2)
    rygates<2, 0>(strig, dc, dsn, lane, A0r, A0i, A1r, A1i);
    rzlayer<2>(wrz, lane, A0r, A0i, A1r, A1i);
    // CNOT block 3 deferred (λ -> LAM3, folded into feature masks)

#pragma unroll
    for (int e = 0; e < 2; ++e) {
        float p0 = A0r[e] * A0r[e] + A0i[e] * A0i[e];
        float p1 = A1r[e] * A1r[e] + A1i[e] * A1i[e];
        float tp = p0 + p1;   // physical-Walsh masks with bit6 = 0
        float tm = p0 - p1;   // physical-Walsh masks with bit6 = 1

        bfly<1>(lane, tp, tm);
        bfly<2>(lane, tp, tm);
        bfly<4>(lane, tp, tm);
        bfly<8>(lane, tp, tm);
        bfly<16>(lane, tp, tm);
        bfly<32>(lane, tp, tm);

        feats<0>(lane, tp, tm, q_out + (size_t)(e0 + e) * 14);
    }
}

// ---------------------------------------------------------------------------
// One MFMA layer: Y[64][N] = act(X[64][K] @ Wt^T + b) into LDS (bf16).
// ---------------------------------------------------------------------------
template<int K, int NTILES, bool RELU>
__device__ __forceinline__ void layer_mfma(
    const unsigned short* src, unsigned short* dst,
    const unsigned short* __restrict__ wt, const float* __restrict__ bias,
    int dstcol, int lane, int wv)
{
    constexpr int KB   = K / 32;
    constexpr int NT_W = (NTILES > 4) ? NTILES / 4 : 1;
    constexpr int MT_W = NTILES / NT_W;
    const int ntile0 = (wv * NT_W) % NTILES;
    const int mtile0 = ((wv * NT_W) / NTILES) * MT_W;
    const int lcol = lane & 15;
    const int lrow = lane >> 4;

    bf16x8 bfrag[NT_W][KB];
    float  bb[NT_W];
#pragma unroll
    for (int n = 0; n < NT_W; ++n) {
#pragma unroll
        for (int kb = 0; kb < KB; ++kb)
            bfrag[n][kb] = *(const bf16x8*)&wt[((ntile0 + n) * 16 + lcol) * K + kb * 32 + lrow * 8];
        bb[n] = bias[(ntile0 + n) * 16 + lcol];
    }

#pragma unroll
    for (int m = 0; m < MT_W; ++m) {
        bf16x8 afrag[KB];
#pragma unroll
        for (int kb = 0; kb < KB; ++kb)
            afrag[kb] = *(const bf16x8*)&src[((mtile0 + m) * 16 + lcol) * LDS_S + kb * 32 + lrow * 8];

        f32x4 acc[NT_W];
#pragma unroll
        for (int n = 0; n < NT_W; ++n) acc[n] = (f32x4){bb[n], bb[n], bb[n], bb[n]};
#pragma unroll
        for (int kb = 0; kb < KB; ++kb)
#pragma unroll
            for (int n = 0; n < NT_W; ++n)
                acc[n] = __builtin_amdgcn_mfma_f32_16x16x32_bf16(afrag[kb], bfrag[n][kb], acc[n], 0, 0, 0);

#pragma unroll
        for (int n = 0; n < NT_W; ++n)
#pragma unroll
            for (int r = 0; r < 4; ++r) {
                float v = acc[n][r];
                if (RELU) v = fmaxf(v, 0.0f);
                dst[((mtile0 + m) * 16 + lrow * 4 + r) * LDS_S + dstcol + (ntile0 + n) * 16 + lcol] = f2bf(v);
            }
    }
}

// ---------------------------------------------------------------------------
// Fused MFMA MLP: 64 rows/block, 256 threads (4 waves).
// ---------------------------------------------------------------------------
__global__ __launch_bounds__(256, 4) void mlp_kernel(
    const float* __restrict__ q_out, const float* __restrict__ x_c,
    const unsigned short* __restrict__ ew1t, const float* __restrict__ eb1,
    const unsigned short* __restrict__ ew2t, const float* __restrict__ eb2,
    const unsigned short* __restrict__ w1t,  const float* __restrict__ b1,
    const unsigned short* __restrict__ w2t,  const float* __restrict__ b2,
    const unsigned short* __restrict__ w3t,  const float* __restrict__ b3,
    const unsigned short* __restrict__ w4t,  const float* __restrict__ b4,
    float* __restrict__ out, int B)
{
    __shared__ unsigned short BufA[ROWS * LDS_S];
    __shared__ unsigned short BufB[ROWS * LDS_S];

    const int tid  = threadIdx.x;
    const int lane = tid & 63;
    const int wv   = __builtin_amdgcn_readfirstlane(tid >> 6);
    const int base = blockIdx.x * ROWS;

    {
        const float4* xr = (const float4*)(x_c + (size_t)base * 64);
        for (int i = tid; i < 1024; i += 256) {
            int row = i >> 4, fc = i & 15;
            float4 v = xr[i];
            us4 b;
            b.x = f2bf(v.x); b.y = f2bf(v.y); b.z = f2bf(v.z); b.w = f2bf(v.w);
            *(us4*)&BufA[row * LDS_S + fc * 4] = b;
        }
    }
    for (int i = tid; i < 64 * 14; i += 256) {
        int row = i / 14, k = i - row * 14;
        BufA[row * LDS_S + 64 + k] = f2bf(q_out[(size_t)(base + row) * 14 + k]);
    }
    for (int i = tid; i < 64 * 18; i += 256) {
        int row = i / 18, k = i - row * 18;
        BufA[row * LDS_S + 110 + k] = 0;
    }
    __syncthreads();

    layer_mfma<64, 4, true>(BufA, BufB, ew1t, eb1, 0, lane, wv);
    __syncthreads();
    layer_mfma<64, 2, true>(BufB, BufA, ew2t, eb2, 78, lane, wv);
    __syncthreads();
    layer_mfma<128, 8, true>(BufA, BufB, w1t, b1, 0, lane, wv);
    __syncthreads();
    layer_mfma<128, 4, true>(BufB, BufA, w2t, b2, 0, lane, wv);
    __syncthreads();
    layer_mfma<64, 2, true>(BufA, BufB, w3t, b3, 0, lane, wv);
    __syncthreads();

    {
        const int lcol = lane & 15;
        const int lrow = lane >> 4;
        bf16x8 a = *(const bf16x8*)&BufB[(wv * 16 + lcol) * LDS_S + lrow * 8];
        bf16x8 b = *(const bf16x8*)&w4t[lcol * 32 + lrow * 8];
        float bv = b4[0];
        f32x4 acc = (f32x4){bv, bv, bv, bv};
        acc = __builtin_amdgcn_mfma_f32_16x16x32_bf16(a, b, acc, 0, 0, 0);
        if (lcol == 0) {
            float4 o; o.x = acc[0]; o.y = acc[1]; o.z = acc[2]; o.w = acc[3];
            *(float4*)(out + base + wv * 16 + lrow * 4) = o;
        }
    }
}

// ---------------------------------------------------------------------------
extern "C" void kernel_launch(void* const* d_in, const int* in_sizes, int n_in,
                              void* d_out, int out_size, void* d_ws, size_t ws_size,
                              hipStream_t stream)
{
    const float* x_q     = (const float*)d_in[0];
    const float* x_c     = (const float*)d_in[1];
    const float* scales  = (const float*)d_in[2];
    const float* biases  = (const float*)d_in[3];
    const float* wry     = (const float*)d_in[4];
    const float* wrz     = (const float*)d_in[5];
    const float* enc_w1  = (const float*)d_in[6];
    const float* enc_b1  = (const float*)d_in[7];
    const float* enc_w2  = (const float*)d_in[8];
    const float* enc_b2  = (const float*)d_in[9];
    const float* fus_w1  = (const float*)d_in[10];
    const float* fus_b1  = (const float*)d_in[11];
    const float* fus_w2  = (const float*)d_in[12];
    const float* fus_b2  = (const float*)d_in[13];
    const float* fus_w3  = (const float*)d_in[14];
    const float* fus_b3  = (const float*)d_in[15];
    const float* fus_w4  = (const float*)d_in[16];
    const float* fus_b4  = (const float*)d_in[17];
    float* out = (float*)d_out;

    int B = in_sizes[0] / NQ;   // 32768

    float* ws    = (float*)d_ws;
    float* q_out = ws;                              // B*14 floats
    unsigned short* wsh = (unsigned short*)(q_out + (size_t)B * 14);
    unsigned short* w1t  = wsh;                     // 16384
    unsigned short* w2t  = w1t + 16384;             // 8192
    unsigned short* ew1t = w2t + 8192;              // 4096
    unsigned short* ew2t = ew1t + 4096;             // 2048
    unsigned short* w3t  = ew2t + 2048;             // 2048
    unsigned short* w4t  = w3t + 2048;              // 512

    int circ_blocks = ((B / 2) * 64 + 255) / 256;   // 2 elements per wave
    circuit_kernel<<<circ_blocks, 256, 0, stream>>>(
        x_q, scales, biases, wry, wrz,
        enc_w1, enc_w2, fus_w1, fus_w2, fus_w3, fus_w4,
        q_out, ew1t, ew2t, w1t, w2t, w3t, w4t, B);

    int row_blocks = B / ROWS;   // 512
    mlp_kernel<<<row_blocks, 256, 0, stream>>>(q_out, x_c,
                                               ew1t, enc_b1, ew2t, enc_b2,
                                               w1t, fus_b1, w2t, fus_b2,
                                               w3t, fus_b3, w4t, fus_b4,
                                               out, B);
}